// Round 18
// baseline (433.515 us; speedup 1.0000x reference)
//
#include <hip/hip_runtime.h>
#include <hip/hip_bf16.h>

typedef __attribute__((ext_vector_type(8))) short bf16x8;
typedef __attribute__((ext_vector_type(4))) float f32x4;
typedef unsigned int __attribute__((address_space(1))) as1_uint;
typedef unsigned int __attribute__((address_space(3))) as3_uint;

#define TXT 256
#define VIDN 1792
#define SEQ 2048
#define HID 3072
#define NH 48
#define HD 64
// attention scale 0.125 folded with log2(e) so softmax uses exp2 directly
#define QSCALE 0.18033688011112042f

__device__ __forceinline__ unsigned short f2bf(float f) {
  union { float f; unsigned int u; } x; x.f = f;
  unsigned int r = x.u + 0x7fffu + ((x.u >> 16) & 1u);
  return (unsigned short)(r >> 16);
}

__device__ __forceinline__ void gload16(const void* g, void* l) {
  __builtin_amdgcn_global_load_lds((const as1_uint*)g, (as3_uint*)l, 16, 0, 0);
}

// fenced raw barrier: no vmcnt drain (unlike __syncthreads), but compiler-fenced
__device__ __forceinline__ void fbar() {
  asm volatile("" ::: "memory");
  __builtin_amdgcn_s_barrier();
  asm volatile("" ::: "memory");
}

// ---------------- fp32 -> bf16 convert ----------------
__global__ __launch_bounds__(256) void cvt_kernel(const float* __restrict__ s,
                                                  unsigned short* __restrict__ d, int n) {
  int i = (blockIdx.x * 256 + threadIdx.x) * 4;
  if (i >= n) return;
  float4 v = *(const float4*)(s + i);
  ushort4 o;
  o.x = f2bf(v.x); o.y = f2bf(v.y); o.z = f2bf(v.z); o.w = f2bf(v.w);
  *(ushort4*)(d + i) = o;
}

// combined + Wq + Wk + Wv -> bf16 in ONE launch (Abf, then Wqkv contiguous)
__global__ __launch_bounds__(256) void cvt4_kernel(
    const float* __restrict__ comb, const float* __restrict__ wq,
    const float* __restrict__ wk, const float* __restrict__ wv,
    unsigned short* __restrict__ abf, unsigned short* __restrict__ wqkv) {
  const int CB = (SEQ * HID) / 1024;   // 6144 blocks for combined
  const int WB = (HID * HID) / 1024;   // 9216 blocks per weight
  int bid = blockIdx.x;
  const float* s; unsigned short* d; int r;
  if (bid < CB) { s = comb; d = abf; r = bid; }
  else {
    int q = bid - CB; int m = q / WB; r = q - m * WB;
    s = (m == 0) ? wq : (m == 1) ? wk : wv;
    d = wqkv + (size_t)m * HID * HID;
  }
  int i = (r * 256 + threadIdx.x) * 4;
  float4 v = *(const float4*)(s + i);
  ushort4 o;
  o.x = f2bf(v.x); o.y = f2bf(v.y); o.z = f2bf(v.z); o.w = f2bf(v.w);
  *(ushort4*)(d + i) = o;
}

// ---------- 128x256-tile BK=64 phase-interleaved bf16 GEMM, C = A * Bt^T ----------
// QKV GEMM plateau: rounds 12-17 tried 5 structurally distinct schedules
// (2-phase x 3 tiles x {1,3} blk/CU, 4-phase BK=64) -> all ~930-960 TF,
// MfmaUtil 29-31%. Keeping this (round-17) version; invariants documented in
// round-17 header. Swizzle: byte' = byte ^ (((byte>>7)&7)<<4), rule-21 form.
// MODE 0: QKV. cols<6144 -> fp32 Cq[2048][6144]; cols>=6144 -> V: +bv, bf16,
//         transposed Vt[col-6144][s]. MODE 1: +bo, fp32 out, rows vid-first.
template<int MODE>
__global__ __launch_bounds__(512) void gemm8p(
    const unsigned short* __restrict__ A,
    const unsigned short* __restrict__ Bt,
    int K, int ntn,
    float* __restrict__ Cq, unsigned short* __restrict__ Vt, const float* __restrict__ bv,
    float* __restrict__ Cout, const float* __restrict__ bo)
{
  __shared__ unsigned short lds[3 * 24576];  // 144 KiB
  const int tid = threadIdx.x;
  const int mt = blockIdx.x / ntn, nt = blockIdx.x % ntn;
  const int m0 = mt * 128, n0 = nt * 256;
  const int w = tid >> 6, lane = tid & 63, lr = lane & 15, lg = lane >> 4;
  const int wr = w >> 2, wc = w & 3;    // 2M x 4N wave grid; per-wave C: 64 x 64
  f32x4 acc[4][4] = {};
  const int NT = K >> 6;                // 48 K-tiles of 64

  // staging sources (pre-swizzled global), linear LDS dest offsets (bytes)
  const unsigned short *As0, *As1, *Bs0, *Bs1, *Bs2, *Bs3;
  int ao0, ao1, bb0, bb1, bb2, bb3;
  {
    int so, ss;
    so = tid * 16;          ss = so ^ (((so >> 7) & 7) << 4);
    ao0 = so; As0 = A + (size_t)(m0 + (ss >> 7)) * K + ((ss & 127) >> 1);
    so = (512 + tid) * 16;  ss = so ^ (((so >> 7) & 7) << 4);
    ao1 = so; As1 = A + (size_t)(m0 + (ss >> 7)) * K + ((ss & 127) >> 1);
    so = tid * 16;          ss = so ^ (((so >> 7) & 7) << 4);
    bb0 = so; Bs0 = Bt + (size_t)(n0 + (ss >> 7)) * K + ((ss & 127) >> 1);
    so = (512 + tid) * 16;  ss = so ^ (((so >> 7) & 7) << 4);
    bb1 = so; Bs1 = Bt + (size_t)(n0 + (ss >> 7)) * K + ((ss & 127) >> 1);
    so = (1024 + tid) * 16; ss = so ^ (((so >> 7) & 7) << 4);
    bb2 = so; Bs2 = Bt + (size_t)(n0 + (ss >> 7)) * K + ((ss & 127) >> 1);
    so = (1536 + tid) * 16; ss = so ^ (((so >> 7) & 7) << 4);
    bb3 = so; Bs3 = Bt + (size_t)(n0 + (ss >> 7)) * K + ((ss & 127) >> 1);
  }

  // swizzled ds_read element offsets: [k-half][fragment]
  int ra[2][4], rb[2][4];
#pragma unroll
  for (int h = 0; h < 2; ++h) {
#pragma unroll
    for (int f = 0; f < 4; ++f) {
      int r1 = wr * 64 + f * 16 + lr;
      ra[h][f] = (r1 * 64 + h * 32 + lg * 8) ^ ((r1 & 7) << 3);
      int r2 = wc * 64 + f * 16 + lr;
      rb[h][f] = (r2 * 64 + h * 32 + lg * 8) ^ ((r2 & 7) << 3);
    }
  }

#define STAGE_ALL(t)                                                           \
  {                                                                            \
    char* sb_ = (char*)lds + ((t) % 3) * 49152;                                \
    const int kk_ = (t) << 6;                                                  \
    gload16(As0 + kk_, sb_ + ao0);                                             \
    gload16(As1 + kk_, sb_ + ao1);                                             \
    gload16(Bs0 + kk_, sb_ + 16384 + bb0);                                     \
    gload16(Bs1 + kk_, sb_ + 16384 + bb1);                                     \
    gload16(Bs2 + kk_, sb_ + 16384 + bb2);                                     \
    gload16(Bs3 + kk_, sb_ + 16384 + bb3);                                     \
  }

#define MM8(N0, N1)                                                            \
  __builtin_amdgcn_s_setprio(1);                                               \
  acc[0][N0] = __builtin_amdgcn_mfma_f32_16x16x32_bf16(af0, bq0, acc[0][N0], 0, 0, 0); \
  acc[1][N0] = __builtin_amdgcn_mfma_f32_16x16x32_bf16(af1, bq0, acc[1][N0], 0, 0, 0); \
  acc[2][N0] = __builtin_amdgcn_mfma_f32_16x16x32_bf16(af2, bq0, acc[2][N0], 0, 0, 0); \
  acc[3][N0] = __builtin_amdgcn_mfma_f32_16x16x32_bf16(af3, bq0, acc[3][N0], 0, 0, 0); \
  acc[0][N1] = __builtin_amdgcn_mfma_f32_16x16x32_bf16(af0, bq1, acc[0][N1], 0, 0, 0); \
  acc[1][N1] = __builtin_amdgcn_mfma_f32_16x16x32_bf16(af1, bq1, acc[1][N1], 0, 0, 0); \
  acc[2][N1] = __builtin_amdgcn_mfma_f32_16x16x32_bf16(af2, bq1, acc[2][N1], 0, 0, 0); \
  acc[3][N1] = __builtin_amdgcn_mfma_f32_16x16x32_bf16(af3, bq1, acc[3][N1], 0, 0, 0); \
  __builtin_amdgcn_s_setprio(0);

#define ITER(t, SG, VMC)                                                       \
  {                                                                            \
    const unsigned short* lA = lds + ((t) % 3) * 24576;                        \
    const unsigned short* lB = lA + 8192;                                      \
    char* sb = (char*)lds + (((t) + 2) % 3) * 49152;                           \
    const int kk = ((t) + 2) << 6;                                             \
    bf16x8 af0, af1, af2, af3, bq0, bq1;                                       \
    /* phase 0: k-half 0, nf 0-1 */                                            \
    af0 = *(const bf16x8*)&lA[ra[0][0]];                                       \
    af1 = *(const bf16x8*)&lA[ra[0][1]];                                       \
    af2 = *(const bf16x8*)&lA[ra[0][2]];                                       \
    af3 = *(const bf16x8*)&lA[ra[0][3]];                                       \
    bq0 = *(const bf16x8*)&lB[rb[0][0]];                                       \
    bq1 = *(const bf16x8*)&lB[rb[0][1]];                                       \
    if (SG) { gload16(As0 + kk, sb + ao0); gload16(As1 + kk, sb + ao1); }      \
    fbar();                                                                    \
    MM8(0, 1)                                                                  \
    fbar();                                                                    \
    /* phase 1: k-half 0, nf 2-3 */                                            \
    bq0 = *(const bf16x8*)&lB[rb[0][2]];                                       \
    bq1 = *(const bf16x8*)&lB[rb[0][3]];                                       \
    if (SG) { gload16(Bs0 + kk, sb + 16384 + bb0);                             \
              gload16(Bs1 + kk, sb + 16384 + bb1); }                           \
    fbar();                                                                    \
    MM8(2, 3)                                                                  \
    fbar();                                                                    \
    /* phase 2: k-half 1, nf 0-1 */                                            \
    af0 = *(const bf16x8*)&lA[ra[1][0]];                                       \
    af1 = *(const bf16x8*)&lA[ra[1][1]];                                       \
    af2 = *(const bf16x8*)&lA[ra[1][2]];                                       \
    af3 = *(const bf16x8*)&lA[ra[1][3]];                                       \
    bq0 = *(const bf16x8*)&lB[rb[1][0]];                                       \
    bq1 = *(const bf16x8*)&lB[rb[1][1]];                                       \
    if (SG) { gload16(Bs2 + kk, sb + 16384 + bb2);                             \
              gload16(Bs3 + kk, sb + 16384 + bb3); }                           \
    fbar();                                                                    \
    MM8(0, 1)                                                                  \
    fbar();                                                                    \
    /* phase 3: k-half 1, nf 2-3; iteration-boundary vmcnt */                  \
    bq0 = *(const bf16x8*)&lB[rb[1][2]];                                       \
    bq1 = *(const bf16x8*)&lB[rb[1][3]];                                       \
    VMC;                                                                       \
    fbar();                                                                    \
    MM8(2, 3)                                                                  \
    fbar();                                                                    \
  }

  STAGE_ALL(0);
  STAGE_ALL(1);
  asm volatile("s_waitcnt vmcnt(6)" ::: "memory");  // tile 0 drained, tile 1 in flight
  fbar();
  int t = 0;
  for (; t < NT - 2; ++t)
    ITER(t, 1, asm volatile("s_waitcnt vmcnt(6)" ::: "memory"));
  ITER(t, 0, asm volatile("s_waitcnt vmcnt(0)" ::: "memory"));
  ++t;
  ITER(t, 0, ((void)0));
#undef STAGE_ALL
#undef MM8
#undef ITER

  if (MODE == 0) {
    if (n0 < 6144) {
#pragma unroll
      for (int mf = 0; mf < 4; ++mf) {
        int row = m0 + wr * 64 + mf * 16 + lg * 4;
#pragma unroll
        for (int nf = 0; nf < 4; ++nf) {
          int col = n0 + wc * 64 + nf * 16 + lr;
#pragma unroll
          for (int j = 0; j < 4; ++j)
            Cq[(size_t)(row + j) * 6144 + col] = acc[mf][nf][j];
        }
      }
    } else {
#pragma unroll
      for (int mf = 0; mf < 4; ++mf) {
        int srow2 = m0 + wr * 64 + mf * 16 + lg * 4;
#pragma unroll
        for (int nf = 0; nf < 4; ++nf) {
          int n2 = n0 - 6144 + wc * 64 + nf * 16 + lr;
          float b = bv[n2];
          ushort4 pk;
          pk.x = f2bf(acc[mf][nf][0] + b);
          pk.y = f2bf(acc[mf][nf][1] + b);
          pk.z = f2bf(acc[mf][nf][2] + b);
          pk.w = f2bf(acc[mf][nf][3] + b);
          *(ushort4*)(Vt + (size_t)n2 * SEQ + srow2) = pk;
        }
      }
    }
  } else {
#pragma unroll
    for (int mf = 0; mf < 4; ++mf) {
      int row = m0 + wr * 64 + mf * 16 + lg * 4;
#pragma unroll
      for (int nf = 0; nf < 4; ++nf) {
        int col = n0 + wc * 64 + nf * 16 + lr;
        float b = bo[col];
#pragma unroll
        for (int j = 0; j < 4; ++j) {
          int s = row + j;
          int orow = (s >= TXT) ? (s - TXT) : (VIDN + s);
          Cout[(size_t)orow * HID + col] = acc[mf][nf][j] + b;
        }
      }
    }
  }
}

// ---------------- LayerNorm + head-indexed RoPE ----------------
// one wave per (s, h, qk): LN over 64 dims, rope for s>=TXT, Q scaled by QSCALE.
__global__ __launch_bounds__(256) void ln_rope_kernel(
    const float* __restrict__ QK,
    const float* __restrict__ bq, const float* __restrict__ bk,
    const float* __restrict__ gq, const float* __restrict__ bgq,
    const float* __restrict__ gk, const float* __restrict__ bgk,
    const float* __restrict__ freqs,
    unsigned short* __restrict__ Qh, unsigned short* __restrict__ Kh)
{
  int wid = blockIdx.x * 4 + (threadIdx.x >> 6);
  int lane = threadIdx.x & 63;
  int s = wid / 96;
  int rem = wid - s * 96;
  int h = rem >> 1, qk = rem & 1;
  int col = h * 64 + lane;
  float x = QK[(size_t)s * 6144 + qk * 3072 + col] + (qk ? bk[col] : bq[col]);
  float m = x;
#pragma unroll
  for (int msk = 1; msk < 64; msk <<= 1) m += __shfl_xor(m, msk);
  float mu = m * (1.0f / 64.0f);
  float xc = x - mu;
  float v = xc * xc;
#pragma unroll
  for (int msk = 1; msk < 64; msk <<= 1) v += __shfl_xor(v, msk);
  float rstd = rsqrtf(v * (1.0f / 64.0f) + 1e-5f);
  float y = xc * rstd * (qk ? gk[lane] : gq[lane]) + (qk ? bgk[lane] : bgq[lane]);
  if (s >= TXT) {
    // out[2d+j] = f[h][d][j][0]*x[2d] + f[h][d][j][1]*x[2d+1]; freqs head-indexed
    float p = __shfl_xor(y, 1);
    float xe = (lane & 1) ? p : y;
    float xo = (lane & 1) ? y : p;
    int base = h * 128 + (lane >> 1) * 4 + (lane & 1) * 2;
    y = freqs[base] * xe + freqs[base + 1] * xo;
  }
  if (!qk) y *= QSCALE;  // fold attention scale (and log2e for exp2-softmax) into Q
  (qk ? Kh : Qh)[((size_t)h * SEQ + s) * 64 + lane] = f2bf(y);
}

// ---------------- flash attention (swapped-QK^T softmax, QBLK=256) ----------------
// ROUND-18: two independent q-groups per block (QBLK 128->256). Per K/V stage
// each wave processes groups g=0,1 (statically unrolled, rule-20): independent
// dependency chains interleave (T15 mechanism) and staging/barriers amortize
// over 2x work; fattn K/V FETCH halves. grid: 48 heads x 8 tiles = 384 blocks.
// Same proven dbuf skeleton: { FSTAGE(t+1)=2 gloads; vmcnt(2); fbar;
// compute g0; compute g1; fbar }. pl slice reused sequentially per wave
// (same-wave write->read, lgkmcnt-ordered).
// St = mfma(K,Q) puts q on lane&15: row-reduce = 15 in-reg ops + 2 shuffles.
__global__ __launch_bounds__(512) void fattn_kernel(
    const unsigned short* __restrict__ Qh, const unsigned short* __restrict__ Kh,
    const unsigned short* __restrict__ Vt, unsigned short* __restrict__ ctx)
{
  __shared__ unsigned short kt[2][2][64][32];  // [slot][half][row][col]
  __shared__ unsigned short vt[2][2][64][32];
  __shared__ unsigned short pl[8][16][72];
  const int h = blockIdx.x >> 3;
  const int q0 = (blockIdx.x & 7) * 256;
  const int tid = threadIdx.x, w = tid >> 6, lane = tid & 63, lr = lane & 15, lg = lane >> 4;

  bf16x8 qfA0, qfA1, qfB0, qfB1;
  {
    const unsigned short* qp = Qh + ((size_t)h * SEQ + q0 + w * 16 + lr) * 64 + lg * 8;
    qfA0 = *(const bf16x8*)qp;
    qfA1 = *(const bf16x8*)(qp + 32);
    qp += (size_t)128 * 64;
    qfB0 = *(const bf16x8*)qp;
    qfB1 = *(const bf16x8*)(qp + 32);
  }
  f32x4 oaccA[4] = {}, oaccB[4] = {};
  float mrunA = -1e30f, lrunA = 0.f, mrunB = -1e30f, lrunB = 0.f;

  // per-thread staging addresses (fixed row/half/col; kv advances the source)
  const int soff = tid * 16;
  const int shalf = soff >> 12;
  const int srem = soff & 4095;
  const int srow = srem >> 6, scb = srem & 63;
  const unsigned short* Ksrc = Kh + ((size_t)h * SEQ + srow) * 64 + shalf * 32 + (scb >> 1);
  const unsigned short* Vsrc = Vt + ((size_t)(h * 64 + srow)) * SEQ + shalf * 32 + (scb >> 1);

#define FSTAGE(t)                                                              \
  {                                                                            \
    const int sl_ = (t) & 1;                                                   \
    const int kv0_ = (t) << 6;                                                 \
    gload16(Ksrc + (size_t)kv0_ * 64, (char*)kt + sl_ * 8192 + soff);          \
    gload16(Vsrc + kv0_, (char*)vt + sl_ * 8192 + soff);                       \
  }

// one q-group's QK^T + online softmax + PV for tile slot `sl`
#define GROUP(QF0, QF1, OACC, MRUN, LRUN)                                      \
  {                                                                            \
    f32x4 sacc[4] = {};                                                        \
    __builtin_amdgcn_s_setprio(1);                                             \
    _Pragma("unroll")                                                          \
    for (int nf = 0; nf < 4; ++nf) {                                           \
      bf16x8 a0 = *(const bf16x8*)&kt[sl][0][nf * 16 + lr][lg * 8];            \
      bf16x8 a1 = *(const bf16x8*)&kt[sl][1][nf * 16 + lr][lg * 8];            \
      sacc[nf] = __builtin_amdgcn_mfma_f32_16x16x32_bf16(a0, QF0, sacc[nf], 0, 0, 0); \
      sacc[nf] = __builtin_amdgcn_mfma_f32_16x16x32_bf16(a1, QF1, sacc[nf], 0, 0, 0); \
    }                                                                          \
    __builtin_amdgcn_s_setprio(0);                                             \
    float mx;                                                                  \
    {                                                                          \
      float t0 = fmaxf(fmaxf(sacc[0][0], sacc[0][1]), fmaxf(sacc[0][2], sacc[0][3])); \
      float t1 = fmaxf(fmaxf(sacc[1][0], sacc[1][1]), fmaxf(sacc[1][2], sacc[1][3])); \
      float t2 = fmaxf(fmaxf(sacc[2][0], sacc[2][1]), fmaxf(sacc[2][2], sacc[2][3])); \
      float t3 = fmaxf(fmaxf(sacc[3][0], sacc[3][1]), fmaxf(sacc[3][2], sacc[3][3])); \
      mx = fmaxf(fmaxf(t0, t1), fmaxf(t2, t3));                                \
    }                                                                          \
    mx = fmaxf(mx, __shfl_xor(mx, 16));                                        \
    mx = fmaxf(mx, __shfl_xor(mx, 32));                                        \
    if (!__all(mx <= MRUN + 8.0f)) {                                           \
      float mn = fmaxf(MRUN, mx);                                              \
      float corr = exp2f(MRUN - mn);                                           \
      LRUN *= corr;                                                            \
      MRUN = mn;                                                               \
      float c0 = __shfl(corr, lg * 4 + 0);                                     \
      float c1 = __shfl(corr, lg * 4 + 1);                                     \
      float c2 = __shfl(corr, lg * 4 + 2);                                     \
      float c3 = __shfl(corr, lg * 4 + 3);                                     \
      _Pragma("unroll")                                                        \
      for (int df = 0; df < 4; ++df) {                                         \
        OACC[df][0] *= c0; OACC[df][1] *= c1;                                  \
        OACC[df][2] *= c2; OACC[df][3] *= c3;                                  \
      }                                                                        \
    }                                                                          \
    float pr[4][4];                                                            \
    _Pragma("unroll")                                                          \
    for (int nf = 0; nf < 4; ++nf)                                             \
      _Pragma("unroll")                                                        \
      for (int r = 0; r < 4; ++r)                                              \
        pr[nf][r] = exp2f(sacc[nf][r] - MRUN);                                 \
    float rs;                                                                  \
    {                                                                          \
      float s0 = (pr[0][0] + pr[0][1]) + (pr[0][2] + pr[0][3]);                \
      float s1 = (pr[1][0] + pr[1][1]) + (pr[1][2] + pr[1][3]);                \
      float s2 = (pr[2][0] + pr[2][1]) + (pr[2][2] + pr[2][3]);                \
      float s3 = (pr[3][0] + pr[3][1]) + (pr[3][2] + pr[3][3]);                \
      rs = (s0 + s1) + (s2 + s3);                                              \
    }                                                                          \
    rs += __shfl_xor(rs, 16);                                                  \
    rs += __shfl_xor(rs, 32);                                                  \
    LRUN += rs;                                                                \
    _Pragma("unroll")                                                          \
    for (int nf = 0; nf < 4; ++nf) {                                           \
      union { __hip_bfloat162 h; unsigned int u; } c0, c1;                     \
      c0.h = __float22bfloat162_rn(make_float2(pr[nf][0], pr[nf][1]));         \
      c1.h = __float22bfloat162_rn(make_float2(pr[nf][2], pr[nf][3]));         \
      uint2 pw; pw.x = c0.u; pw.y = c1.u;                                      \
      *(uint2*)&pl[w][lr][nf * 16 + lg * 4] = pw;                              \
    }                                                                          \
    bf16x8 pa0 = *(const bf16x8*)&pl[w][lr][lg * 8];                           \
    bf16x8 pa1 = *(const bf16x8*)&pl[w][lr][32 + lg * 8];                      \
    __builtin_amdgcn_s_setprio(1);                                             \
    _Pragma("unroll")                                                          \
    for (int df = 0; df < 4; ++df) {                                           \
      bf16x8 v0 = *(const bf16x8*)&vt[sl][0][df * 16 + lr][lg * 8];            \
      bf16x8 v1 = *(const bf16x8*)&vt[sl][1][df * 16 + lr][lg * 8];            \
      OACC[df] = __builtin_amdgcn_mfma_f32_16x16x32_bf16(pa0, v0, OACC[df], 0, 0, 0); \
      OACC[df] = __builtin_amdgcn_mfma_f32_16x16x32_bf16(pa1, v1, OACC[df], 0, 0, 0); \
    }                                                                          \
    __builtin_amdgcn_s_setprio(0);                                             \
  }

  FSTAGE(0);
  for (int t = 0; t < 32; ++t) {
    const int sl = t & 1;
    if (t < 31) {
      FSTAGE(t + 1);
      asm volatile("s_waitcnt vmcnt(2)" ::: "memory");
    } else {
      asm volatile("s_waitcnt vmcnt(0)" ::: "memory");
    }
    fbar();   // all waves' tile-t K/V writes now in LDS
    GROUP(qfA0, qfA1, oaccA, mrunA, lrunA)
    GROUP(qfB0, qfB1, oaccB, mrunB, lrunB)
    fbar();   // all waves done reading slot sl before it is re-staged
  }
#undef FSTAGE
#undef GROUP

  // epilogue: move 1/lrun (at q=lane&15 layout) to C-layout rows via shfl
  {
    float linv = 1.0f / lrunA;
    float i0 = __shfl(linv, lg * 4 + 0);
    float i1 = __shfl(linv, lg * 4 + 1);
    float i2 = __shfl(linv, lg * 4 + 2);
    float i3 = __shfl(linv, lg * 4 + 3);
#pragma unroll
    for (int df = 0; df < 4; ++df) {
      int s = q0 + w * 16 + lg * 4;
      int dcol = h * 64 + df * 16 + lr;
      ctx[(size_t)(s + 0) * HID + dcol] = f2bf(oaccA[df][0] * i0);
      ctx[(size_t)(s + 1) * HID + dcol] = f2bf(oaccA[df][1] * i1);
      ctx[(size_t)(s + 2) * HID + dcol] = f2bf(oaccA[df][2] * i2);
      ctx[(size_t)(s + 3) * HID + dcol] = f2bf(oaccA[df][3] * i3);
    }
  }
  {
    float linv = 1.0f / lrunB;
    float i0 = __shfl(linv, lg * 4 + 0);
    float i1 = __shfl(linv, lg * 4 + 1);
    float i2 = __shfl(linv, lg * 4 + 2);
    float i3 = __shfl(linv, lg * 4 + 3);
#pragma unroll
    for (int df = 0; df < 4; ++df) {
      int s = q0 + 128 + w * 16 + lg * 4;
      int dcol = h * 64 + df * 16 + lr;
      ctx[(size_t)(s + 0) * HID + dcol] = f2bf(oaccB[df][0] * i0);
      ctx[(size_t)(s + 1) * HID + dcol] = f2bf(oaccB[df][1] * i1);
      ctx[(size_t)(s + 2) * HID + dcol] = f2bf(oaccB[df][2] * i2);
      ctx[(size_t)(s + 3) * HID + dcol] = f2bf(oaccB[df][3] * i3);
    }
  }
}

extern "C" void kernel_launch(void* const* d_in, const int* in_sizes, int n_in,
                              void* d_out, int out_size, void* d_ws, size_t ws_size,
                              hipStream_t stream) {
  const float* combined = (const float*)d_in[0];
  const float* freqs    = (const float*)d_in[1];
  const float* Wq  = (const float*)d_in[2];
  const float* bq  = (const float*)d_in[3];
  const float* Wk  = (const float*)d_in[4];
  const float* bk  = (const float*)d_in[5];
  const float* Wv  = (const float*)d_in[6];
  const float* bv  = (const float*)d_in[7];
  const float* Wo  = (const float*)d_in[8];
  const float* bo  = (const float*)d_in[9];
  const float* gq  = (const float*)d_in[10];
  const float* bgq = (const float*)d_in[11];
  const float* gk  = (const float*)d_in[12];
  const float* bgk = (const float*)d_in[13];
  float* out = (float*)d_out;  // reference output dtype is float32

  char* ws = (char*)d_ws;
  unsigned short* Abf  = (unsigned short*)ws; ws += (size_t)SEQ * HID * 2;    // reused as ctx
  unsigned short* Wqkv = (unsigned short*)ws; ws += (size_t)3 * HID * HID * 2;
  float*          QK   = (float*)ws;          ws += (size_t)SEQ * 6144 * 4;   // reused for Wob
  unsigned short* Qh   = (unsigned short*)ws; ws += (size_t)NH * SEQ * HD * 2;
  unsigned short* Kh   = (unsigned short*)ws; ws += (size_t)NH * SEQ * HD * 2;
  unsigned short* Vt   = (unsigned short*)ws; ws += (size_t)NH * HD * SEQ * 2;
  unsigned short* Wob  = (unsigned short*)QK;   // alias: QK dead after ln_rope
  unsigned short* ctx  = Abf;                   // alias: Abf dead after QKV GEMM

  // combined + Wq + Wk + Wv -> bf16 in one launch
  cvt4_kernel<<<(SEQ * HID) / 1024 + 3 * (HID * HID) / 1024, 256, 0, stream>>>(
      combined, Wq, Wk, Wv, Abf, Wqkv);

  // QKV GEMM: M=2048, N=9216, K=3072 -> 16x36 = 576 blocks of 128x256, BK=64
  gemm8p<0><<<16 * 36, 512, 0, stream>>>(Abf, Wqkv, HID, 36, QK, Vt, bv, nullptr, nullptr);

  // LN + rope: 2048*48*2 waves
  ln_rope_kernel<<<(SEQ * NH * 2) / 4, 256, 0, stream>>>(QK, bq, bk, gq, bgq, gk, bgk, freqs, Qh, Kh);

  // Wo -> bf16 into the (now dead) QK region
  cvt_kernel<<<(HID * HID) / 1024, 256, 0, stream>>>(Wo, Wob, HID * HID);

  // flash attention: 48 heads x 8 q-tiles of 256 rows, 512 threads
  fattn_kernel<<<NH * 8, 512, 0, stream>>>(Qh, Kh, Vt, ctx);

  // final GEMM: M=2048, N=3072, K=3072 -> 16x12 = 192 blocks of 128x256
  gemm8p<1><<<16 * 12, 512, 0, stream>>>(ctx, Wob, HID, 12, nullptr, nullptr, nullptr, out, bo);
}

// Round 19
// 401.219 us; speedup vs baseline: 1.0805x; 1.0805x over previous
//
#include <hip/hip_runtime.h>
#include <hip/hip_bf16.h>

typedef __attribute__((ext_vector_type(8))) short bf16x8;
typedef __attribute__((ext_vector_type(4))) float f32x4;
typedef unsigned int __attribute__((address_space(1))) as1_uint;
typedef unsigned int __attribute__((address_space(3))) as3_uint;

#define TXT 256
#define VIDN 1792
#define SEQ 2048
#define HID 3072
#define NH 48
#define HD 64
// attention scale 0.125 folded with log2(e) so softmax uses exp2 directly
#define QSCALE 0.18033688011112042f

__device__ __forceinline__ unsigned short f2bf(float f) {
  union { float f; unsigned int u; } x; x.f = f;
  unsigned int r = x.u + 0x7fffu + ((x.u >> 16) & 1u);
  return (unsigned short)(r >> 16);
}

__device__ __forceinline__ void gload16(const void* g, void* l) {
  __builtin_amdgcn_global_load_lds((const as1_uint*)g, (as3_uint*)l, 16, 0, 0);
}

// fenced raw barrier: no vmcnt drain (unlike __syncthreads), but compiler-fenced
__device__ __forceinline__ void fbar() {
  asm volatile("" ::: "memory");
  __builtin_amdgcn_s_barrier();
  asm volatile("" ::: "memory");
}

// combined + Wq + Wk + Wv + Wo -> bf16 in ONE launch
__global__ __launch_bounds__(256) void cvt5_kernel(
    const float* __restrict__ comb, const float* __restrict__ wq,
    const float* __restrict__ wk, const float* __restrict__ wv,
    const float* __restrict__ wo,
    unsigned short* __restrict__ abf, unsigned short* __restrict__ wqkv,
    unsigned short* __restrict__ wob) {
  const int CB = (SEQ * HID) / 1024;   // 6144 blocks for combined
  const int WB = (HID * HID) / 1024;   // 9216 blocks per weight
  int bid = blockIdx.x;
  const float* s; unsigned short* d; int r;
  if (bid < CB) { s = comb; d = abf; r = bid; }
  else {
    int q = bid - CB; int m = q / WB; r = q - m * WB;
    if (m < 3) { s = (m == 0) ? wq : (m == 1) ? wk : wv; d = wqkv + (size_t)m * HID * HID; }
    else { s = wo; d = wob; }
  }
  int i = (r * 256 + threadIdx.x) * 4;
  float4 v = *(const float4*)(s + i);
  ushort4 o;
  o.x = f2bf(v.x); o.y = f2bf(v.y); o.z = f2bf(v.z); o.w = f2bf(v.w);
  *(ushort4*)(d + i) = o;
}

// ---------- 128x256-tile BK=64 phase-interleaved bf16 GEMM, C = A * Bt^T ----------
// QKV GEMM plateau: rounds 12-17 tried 5 structurally distinct schedules
// (2-phase x 3 tiles x {1,3} blk/CU, 4-phase BK=64) -> all ~930-960 TF,
// MfmaUtil 29-31%. Keeping the round-17 version; invariants in its header.
// Swizzle: byte' = byte ^ (((byte>>7)&7)<<4), rule-21 form.
// MODE 0: QKV. cols<6144 -> fp32 Cq[2048][6144]; cols>=6144 -> V: +bv, bf16,
//         transposed Vt[col-6144][s]. MODE 1: +bo, fp32 out, rows vid-first.
template<int MODE>
__global__ __launch_bounds__(512) void gemm8p(
    const unsigned short* __restrict__ A,
    const unsigned short* __restrict__ Bt,
    int K, int ntn,
    float* __restrict__ Cq, unsigned short* __restrict__ Vt, const float* __restrict__ bv,
    float* __restrict__ Cout, const float* __restrict__ bo)
{
  __shared__ unsigned short lds[3 * 24576];  // 144 KiB
  const int tid = threadIdx.x;
  const int mt = blockIdx.x / ntn, nt = blockIdx.x % ntn;
  const int m0 = mt * 128, n0 = nt * 256;
  const int w = tid >> 6, lane = tid & 63, lr = lane & 15, lg = lane >> 4;
  const int wr = w >> 2, wc = w & 3;    // 2M x 4N wave grid; per-wave C: 64 x 64
  f32x4 acc[4][4] = {};
  const int NT = K >> 6;                // 48 K-tiles of 64

  // staging sources (pre-swizzled global), linear LDS dest offsets (bytes)
  const unsigned short *As0, *As1, *Bs0, *Bs1, *Bs2, *Bs3;
  int ao0, ao1, bb0, bb1, bb2, bb3;
  {
    int so, ss;
    so = tid * 16;          ss = so ^ (((so >> 7) & 7) << 4);
    ao0 = so; As0 = A + (size_t)(m0 + (ss >> 7)) * K + ((ss & 127) >> 1);
    so = (512 + tid) * 16;  ss = so ^ (((so >> 7) & 7) << 4);
    ao1 = so; As1 = A + (size_t)(m0 + (ss >> 7)) * K + ((ss & 127) >> 1);
    so = tid * 16;          ss = so ^ (((so >> 7) & 7) << 4);
    bb0 = so; Bs0 = Bt + (size_t)(n0 + (ss >> 7)) * K + ((ss & 127) >> 1);
    so = (512 + tid) * 16;  ss = so ^ (((so >> 7) & 7) << 4);
    bb1 = so; Bs1 = Bt + (size_t)(n0 + (ss >> 7)) * K + ((ss & 127) >> 1);
    so = (1024 + tid) * 16; ss = so ^ (((so >> 7) & 7) << 4);
    bb2 = so; Bs2 = Bt + (size_t)(n0 + (ss >> 7)) * K + ((ss & 127) >> 1);
    so = (1536 + tid) * 16; ss = so ^ (((so >> 7) & 7) << 4);
    bb3 = so; Bs3 = Bt + (size_t)(n0 + (ss >> 7)) * K + ((ss & 127) >> 1);
  }

  // swizzled ds_read element offsets: [k-half][fragment]
  int ra[2][4], rb[2][4];
#pragma unroll
  for (int h = 0; h < 2; ++h) {
#pragma unroll
    for (int f = 0; f < 4; ++f) {
      int r1 = wr * 64 + f * 16 + lr;
      ra[h][f] = (r1 * 64 + h * 32 + lg * 8) ^ ((r1 & 7) << 3);
      int r2 = wc * 64 + f * 16 + lr;
      rb[h][f] = (r2 * 64 + h * 32 + lg * 8) ^ ((r2 & 7) << 3);
    }
  }

#define STAGE_ALL(t)                                                           \
  {                                                                            \
    char* sb_ = (char*)lds + ((t) % 3) * 49152;                                \
    const int kk_ = (t) << 6;                                                  \
    gload16(As0 + kk_, sb_ + ao0);                                             \
    gload16(As1 + kk_, sb_ + ao1);                                             \
    gload16(Bs0 + kk_, sb_ + 16384 + bb0);                                     \
    gload16(Bs1 + kk_, sb_ + 16384 + bb1);                                     \
    gload16(Bs2 + kk_, sb_ + 16384 + bb2);                                     \
    gload16(Bs3 + kk_, sb_ + 16384 + bb3);                                     \
  }

#define MM8(N0, N1)                                                            \
  __builtin_amdgcn_s_setprio(1);                                               \
  acc[0][N0] = __builtin_amdgcn_mfma_f32_16x16x32_bf16(af0, bq0, acc[0][N0], 0, 0, 0); \
  acc[1][N0] = __builtin_amdgcn_mfma_f32_16x16x32_bf16(af1, bq0, acc[1][N0], 0, 0, 0); \
  acc[2][N0] = __builtin_amdgcn_mfma_f32_16x16x32_bf16(af2, bq0, acc[2][N0], 0, 0, 0); \
  acc[3][N0] = __builtin_amdgcn_mfma_f32_16x16x32_bf16(af3, bq0, acc[3][N0], 0, 0, 0); \
  acc[0][N1] = __builtin_amdgcn_mfma_f32_16x16x32_bf16(af0, bq1, acc[0][N1], 0, 0, 0); \
  acc[1][N1] = __builtin_amdgcn_mfma_f32_16x16x32_bf16(af1, bq1, acc[1][N1], 0, 0, 0); \
  acc[2][N1] = __builtin_amdgcn_mfma_f32_16x16x32_bf16(af2, bq1, acc[2][N1], 0, 0, 0); \
  acc[3][N1] = __builtin_amdgcn_mfma_f32_16x16x32_bf16(af3, bq1, acc[3][N1], 0, 0, 0); \
  __builtin_amdgcn_s_setprio(0);

#define ITER(t, SG, VMC)                                                       \
  {                                                                            \
    const unsigned short* lA = lds + ((t) % 3) * 24576;                        \
    const unsigned short* lB = lA + 8192;                                      \
    char* sb = (char*)lds + (((t) + 2) % 3) * 49152;                           \
    const int kk = ((t) + 2) << 6;                                             \
    bf16x8 af0, af1, af2, af3, bq0, bq1;                                       \
    /* phase 0: k-half 0, nf 0-1 */                                            \
    af0 = *(const bf16x8*)&lA[ra[0][0]];                                       \
    af1 = *(const bf16x8*)&lA[ra[0][1]];                                       \
    af2 = *(const bf16x8*)&lA[ra[0][2]];                                       \
    af3 = *(const bf16x8*)&lA[ra[0][3]];                                       \
    bq0 = *(const bf16x8*)&lB[rb[0][0]];                                       \
    bq1 = *(const bf16x8*)&lB[rb[0][1]];                                       \
    if (SG) { gload16(As0 + kk, sb + ao0); gload16(As1 + kk, sb + ao1); }      \
    fbar();                                                                    \
    MM8(0, 1)                                                                  \
    fbar();                                                                    \
    /* phase 1: k-half 0, nf 2-3 */                                            \
    bq0 = *(const bf16x8*)&lB[rb[0][2]];                                       \
    bq1 = *(const bf16x8*)&lB[rb[0][3]];                                       \
    if (SG) { gload16(Bs0 + kk, sb + 16384 + bb0);                             \
              gload16(Bs1 + kk, sb + 16384 + bb1); }                           \
    fbar();                                                                    \
    MM8(2, 3)                                                                  \
    fbar();                                                                    \
    /* phase 2: k-half 1, nf 0-1 */                                            \
    af0 = *(const bf16x8*)&lA[ra[1][0]];                                       \
    af1 = *(const bf16x8*)&lA[ra[1][1]];                                       \
    af2 = *(const bf16x8*)&lA[ra[1][2]];                                       \
    af3 = *(const bf16x8*)&lA[ra[1][3]];                                       \
    bq0 = *(const bf16x8*)&lB[rb[1][0]];                                       \
    bq1 = *(const bf16x8*)&lB[rb[1][1]];                                       \
    if (SG) { gload16(Bs2 + kk, sb + 16384 + bb2);                             \
              gload16(Bs3 + kk, sb + 16384 + bb3); }                           \
    fbar();                                                                    \
    MM8(0, 1)                                                                  \
    fbar();                                                                    \
    /* phase 3: k-half 1, nf 2-3; iteration-boundary vmcnt */                  \
    bq0 = *(const bf16x8*)&lB[rb[1][2]];                                       \
    bq1 = *(const bf16x8*)&lB[rb[1][3]];                                       \
    VMC;                                                                       \
    fbar();                                                                    \
    MM8(2, 3)                                                                  \
    fbar();                                                                    \
  }

  STAGE_ALL(0);
  STAGE_ALL(1);
  asm volatile("s_waitcnt vmcnt(6)" ::: "memory");  // tile 0 drained, tile 1 in flight
  fbar();
  int t = 0;
  for (; t < NT - 2; ++t)
    ITER(t, 1, asm volatile("s_waitcnt vmcnt(6)" ::: "memory"));
  ITER(t, 0, asm volatile("s_waitcnt vmcnt(0)" ::: "memory"));
  ++t;
  ITER(t, 0, ((void)0));
#undef STAGE_ALL
#undef MM8
#undef ITER

  if (MODE == 0) {
    if (n0 < 6144) {
#pragma unroll
      for (int mf = 0; mf < 4; ++mf) {
        int row = m0 + wr * 64 + mf * 16 + lg * 4;
#pragma unroll
        for (int nf = 0; nf < 4; ++nf) {
          int col = n0 + wc * 64 + nf * 16 + lr;
#pragma unroll
          for (int j = 0; j < 4; ++j)
            Cq[(size_t)(row + j) * 6144 + col] = acc[mf][nf][j];
        }
      }
    } else {
#pragma unroll
      for (int mf = 0; mf < 4; ++mf) {
        int srow2 = m0 + wr * 64 + mf * 16 + lg * 4;
#pragma unroll
        for (int nf = 0; nf < 4; ++nf) {
          int n2 = n0 - 6144 + wc * 64 + nf * 16 + lr;
          float b = bv[n2];
          ushort4 pk;
          pk.x = f2bf(acc[mf][nf][0] + b);
          pk.y = f2bf(acc[mf][nf][1] + b);
          pk.z = f2bf(acc[mf][nf][2] + b);
          pk.w = f2bf(acc[mf][nf][3] + b);
          *(ushort4*)(Vt + (size_t)n2 * SEQ + srow2) = pk;
        }
      }
    }
  } else {
#pragma unroll
    for (int mf = 0; mf < 4; ++mf) {
      int row = m0 + wr * 64 + mf * 16 + lg * 4;
#pragma unroll
      for (int nf = 0; nf < 4; ++nf) {
        int col = n0 + wc * 64 + nf * 16 + lr;
        float b = bo[col];
#pragma unroll
        for (int j = 0; j < 4; ++j) {
          int s = row + j;
          int orow = (s >= TXT) ? (s - TXT) : (VIDN + s);
          Cout[(size_t)orow * HID + col] = acc[mf][nf][j] + b;
        }
      }
    }
  }
}

// ---------------- LayerNorm + head-indexed RoPE ----------------
// one wave per (s, h, qk): LN over 64 dims, rope for s>=TXT, Q scaled by QSCALE.
__global__ __launch_bounds__(256) void ln_rope_kernel(
    const float* __restrict__ QK,
    const float* __restrict__ bq, const float* __restrict__ bk,
    const float* __restrict__ gq, const float* __restrict__ bgq,
    const float* __restrict__ gk, const float* __restrict__ bgk,
    const float* __restrict__ freqs,
    unsigned short* __restrict__ Qh, unsigned short* __restrict__ Kh)
{
  int wid = blockIdx.x * 4 + (threadIdx.x >> 6);
  int lane = threadIdx.x & 63;
  int s = wid / 96;
  int rem = wid - s * 96;
  int h = rem >> 1, qk = rem & 1;
  int col = h * 64 + lane;
  float x = QK[(size_t)s * 6144 + qk * 3072 + col] + (qk ? bk[col] : bq[col]);
  float m = x;
#pragma unroll
  for (int msk = 1; msk < 64; msk <<= 1) m += __shfl_xor(m, msk);
  float mu = m * (1.0f / 64.0f);
  float xc = x - mu;
  float v = xc * xc;
#pragma unroll
  for (int msk = 1; msk < 64; msk <<= 1) v += __shfl_xor(v, msk);
  float rstd = rsqrtf(v * (1.0f / 64.0f) + 1e-5f);
  float y = xc * rstd * (qk ? gk[lane] : gq[lane]) + (qk ? bgk[lane] : bgq[lane]);
  if (s >= TXT) {
    // out[2d+j] = f[h][d][j][0]*x[2d] + f[h][d][j][1]*x[2d+1]; freqs head-indexed
    float p = __shfl_xor(y, 1);
    float xe = (lane & 1) ? p : y;
    float xo = (lane & 1) ? y : p;
    int base = h * 128 + (lane >> 1) * 4 + (lane & 1) * 2;
    y = freqs[base] * xe + freqs[base + 1] * xo;
  }
  if (!qk) y *= QSCALE;  // fold attention scale (and log2e for exp2-softmax) into Q
  (qk ? Kh : Qh)[((size_t)h * SEQ + s) * 64 + lane] = f2bf(y);
}

// ---------------- flash attention (swapped-QK^T softmax) ----------------
// ROUND-17 version (best measured ~90 us; round-18 QBLK=256 regressed: the two
// q-groups serialized through the shared pl slice + VGPR pressure).
// grid: h * 16 q-tiles; 8 waves x 16 q-rows (QBLK=128); BKV=64; D=64.
// Double-buffered K/V staging with counted vmcnt: { FSTAGE(t+1)=2 gloads;
// vmcnt(2); fbar; compute(t); fbar } — staging hides under previous iter's
// compute. Q-loads issue BEFORE FSTAGE(0) (FIFO vmcnt covers them).
// St = mfma(K,Q) puts q on lane&15: row-reduce = 15 in-reg ops + 2 shuffles.
__global__ __launch_bounds__(512) void fattn_kernel(
    const unsigned short* __restrict__ Qh, const unsigned short* __restrict__ Kh,
    const unsigned short* __restrict__ Vt, unsigned short* __restrict__ ctx)
{
  __shared__ unsigned short kt[2][2][64][32];  // [slot][half][row][col]
  __shared__ unsigned short vt[2][2][64][32];
  __shared__ unsigned short pl[8][16][72];
  const int h = blockIdx.x >> 4;
  const int q0 = (blockIdx.x & 15) * 128;
  const int tid = threadIdx.x, w = tid >> 6, lane = tid & 63, lr = lane & 15, lg = lane >> 4;

  bf16x8 qf0, qf1;
  {
    const unsigned short* qp = Qh + ((size_t)h * SEQ + q0 + w * 16 + lr) * 64 + lg * 8;
    qf0 = *(const bf16x8*)qp;
    qf1 = *(const bf16x8*)(qp + 32);
  }
  f32x4 oacc[4] = {};
  float mrun = -1e30f, lrun = 0.f;   // this lane's q-row = q0 + w*16 + lr

  // per-thread staging addresses (fixed row/half/col; kv advances the source)
  const int soff = tid * 16;
  const int shalf = soff >> 12;
  const int srem = soff & 4095;
  const int srow = srem >> 6, scb = srem & 63;
  const unsigned short* Ksrc = Kh + ((size_t)h * SEQ + srow) * 64 + shalf * 32 + (scb >> 1);
  const unsigned short* Vsrc = Vt + ((size_t)(h * 64 + srow)) * SEQ + shalf * 32 + (scb >> 1);

#define FSTAGE(t)                                                              \
  {                                                                            \
    const int sl_ = (t) & 1;                                                   \
    const int kv0_ = (t) << 6;                                                 \
    gload16(Ksrc + (size_t)kv0_ * 64, (char*)kt + sl_ * 8192 + soff);          \
    gload16(Vsrc + kv0_, (char*)vt + sl_ * 8192 + soff);                       \
  }

  FSTAGE(0);
  for (int t = 0; t < 32; ++t) {
    const int sl = t & 1;
    if (t < 31) {
      FSTAGE(t + 1);
      asm volatile("s_waitcnt vmcnt(2)" ::: "memory");
    } else {
      asm volatile("s_waitcnt vmcnt(0)" ::: "memory");
    }
    fbar();   // all waves' tile-t K/V writes now in LDS

    // St[kv][q]: sacc[nf][r] = S[q = lr][kv = t*64 + nf*16 + lg*4 + r]
    f32x4 sacc[4] = {};
    __builtin_amdgcn_s_setprio(1);
#pragma unroll
    for (int nf = 0; nf < 4; ++nf) {
      bf16x8 a0 = *(const bf16x8*)&kt[sl][0][nf * 16 + lr][lg * 8];
      bf16x8 a1 = *(const bf16x8*)&kt[sl][1][nf * 16 + lr][lg * 8];
      sacc[nf] = __builtin_amdgcn_mfma_f32_16x16x32_bf16(a0, qf0, sacc[nf], 0, 0, 0);
      sacc[nf] = __builtin_amdgcn_mfma_f32_16x16x32_bf16(a1, qf1, sacc[nf], 0, 0, 0);
    }
    __builtin_amdgcn_s_setprio(0);

    // tile max over the 16 in-register kv values, then xor16/xor32
    float mx;
    {
      float t0 = fmaxf(fmaxf(sacc[0][0], sacc[0][1]), fmaxf(sacc[0][2], sacc[0][3]));
      float t1 = fmaxf(fmaxf(sacc[1][0], sacc[1][1]), fmaxf(sacc[1][2], sacc[1][3]));
      float t2 = fmaxf(fmaxf(sacc[2][0], sacc[2][1]), fmaxf(sacc[2][2], sacc[2][3]));
      float t3 = fmaxf(fmaxf(sacc[3][0], sacc[3][1]), fmaxf(sacc[3][2], sacc[3][3]));
      mx = fmaxf(fmaxf(t0, t1), fmaxf(t2, t3));
    }
    mx = fmaxf(mx, __shfl_xor(mx, 16));
    mx = fmaxf(mx, __shfl_xor(mx, 32));

    // defer-max (log2 units): only rescale when max grew past threshold
    if (!__all(mx <= mrun + 8.0f)) {
      float mn = fmaxf(mrun, mx);
      float corr = exp2f(mrun - mn);
      lrun *= corr;
      mrun = mn;
      float c0 = __shfl(corr, lg * 4 + 0);
      float c1 = __shfl(corr, lg * 4 + 1);
      float c2 = __shfl(corr, lg * 4 + 2);
      float c3 = __shfl(corr, lg * 4 + 3);
#pragma unroll
      for (int df = 0; df < 4; ++df) {
        oacc[df][0] *= c0; oacc[df][1] *= c1;
        oacc[df][2] *= c2; oacc[df][3] *= c3;
      }
    }

    // P = exp2(S - mrun); row-sum; pack to bf16 and write P[q][kv] as b64
    float pr[4][4];
#pragma unroll
    for (int nf = 0; nf < 4; ++nf)
#pragma unroll
      for (int r = 0; r < 4; ++r)
        pr[nf][r] = exp2f(sacc[nf][r] - mrun);
    float rs;
    {
      float s0 = (pr[0][0] + pr[0][1]) + (pr[0][2] + pr[0][3]);
      float s1 = (pr[1][0] + pr[1][1]) + (pr[1][2] + pr[1][3]);
      float s2 = (pr[2][0] + pr[2][1]) + (pr[2][2] + pr[2][3]);
      float s3 = (pr[3][0] + pr[3][1]) + (pr[3][2] + pr[3][3]);
      rs = (s0 + s1) + (s2 + s3);
    }
    rs += __shfl_xor(rs, 16);
    rs += __shfl_xor(rs, 32);
    lrun += rs;

#pragma unroll
    for (int nf = 0; nf < 4; ++nf) {
      union { __hip_bfloat162 h; unsigned int u; } c0, c1;
      c0.h = __float22bfloat162_rn(make_float2(pr[nf][0], pr[nf][1]));
      c1.h = __float22bfloat162_rn(make_float2(pr[nf][2], pr[nf][3]));
      uint2 pw; pw.x = c0.u; pw.y = c1.u;
      *(uint2*)&pl[w][lr][nf * 16 + lg * 4] = pw;
    }
    // no barrier: pl slice is per-wave; lgkmcnt orders write->read

    bf16x8 pa0 = *(const bf16x8*)&pl[w][lr][lg * 8];
    bf16x8 pa1 = *(const bf16x8*)&pl[w][lr][32 + lg * 8];
    __builtin_amdgcn_s_setprio(1);
#pragma unroll
    for (int df = 0; df < 4; ++df) {
      bf16x8 v0 = *(const bf16x8*)&vt[sl][0][df * 16 + lr][lg * 8];
      bf16x8 v1 = *(const bf16x8*)&vt[sl][1][df * 16 + lr][lg * 8];
      oacc[df] = __builtin_amdgcn_mfma_f32_16x16x32_bf16(pa0, v0, oacc[df], 0, 0, 0);
      oacc[df] = __builtin_amdgcn_mfma_f32_16x16x32_bf16(pa1, v1, oacc[df], 0, 0, 0);
    }
    __builtin_amdgcn_s_setprio(0);

    fbar();   // all waves done reading slot sl before it is re-staged
  }
#undef FSTAGE

  // epilogue: move 1/lrun (at q=lane&15 layout) to C-layout rows via shfl
  float linv = 1.0f / lrun;
  float i0 = __shfl(linv, lg * 4 + 0);
  float i1 = __shfl(linv, lg * 4 + 1);
  float i2 = __shfl(linv, lg * 4 + 2);
  float i3 = __shfl(linv, lg * 4 + 3);
#pragma unroll
  for (int df = 0; df < 4; ++df) {
    int s = q0 + w * 16 + lg * 4;
    int dcol = h * 64 + df * 16 + lr;
    ctx[(size_t)(s + 0) * HID + dcol] = f2bf(oacc[df][0] * i0);
    ctx[(size_t)(s + 1) * HID + dcol] = f2bf(oacc[df][1] * i1);
    ctx[(size_t)(s + 2) * HID + dcol] = f2bf(oacc[df][2] * i2);
    ctx[(size_t)(s + 3) * HID + dcol] = f2bf(oacc[df][3] * i3);
  }
}

extern "C" void kernel_launch(void* const* d_in, const int* in_sizes, int n_in,
                              void* d_out, int out_size, void* d_ws, size_t ws_size,
                              hipStream_t stream) {
  const float* combined = (const float*)d_in[0];
  const float* freqs    = (const float*)d_in[1];
  const float* Wq  = (const float*)d_in[2];
  const float* bq  = (const float*)d_in[3];
  const float* Wk  = (const float*)d_in[4];
  const float* bk  = (const float*)d_in[5];
  const float* Wv  = (const float*)d_in[6];
  const float* bv  = (const float*)d_in[7];
  const float* Wo  = (const float*)d_in[8];
  const float* bo  = (const float*)d_in[9];
  const float* gq  = (const float*)d_in[10];
  const float* bgq = (const float*)d_in[11];
  const float* gk  = (const float*)d_in[12];
  const float* bgk = (const float*)d_in[13];
  float* out = (float*)d_out;  // reference output dtype is float32

  char* ws = (char*)d_ws;
  unsigned short* Abf  = (unsigned short*)ws; ws += (size_t)SEQ * HID * 2;    // reused as ctx
  unsigned short* Wqkv = (unsigned short*)ws; ws += (size_t)3 * HID * HID * 2;
  float*          QK   = (float*)ws;          ws += (size_t)SEQ * 6144 * 4;
  unsigned short* Qh   = (unsigned short*)ws; ws += (size_t)NH * SEQ * HD * 2;
  unsigned short* Kh   = (unsigned short*)ws; ws += (size_t)NH * SEQ * HD * 2;
  unsigned short* Vt   = (unsigned short*)ws; ws += (size_t)NH * HD * SEQ * 2;
  unsigned short* Wob  = (unsigned short*)ws; ws += (size_t)HID * HID * 2;    // 176 MB total < 189 MB proven
  unsigned short* ctx  = Abf;                   // alias: Abf dead after QKV GEMM

  // combined + Wq + Wk + Wv + Wo -> bf16 in one launch
  cvt5_kernel<<<(SEQ * HID) / 1024 + 4 * (HID * HID) / 1024, 256, 0, stream>>>(
      combined, Wq, Wk, Wv, Wo, Abf, Wqkv, Wob);

  // QKV GEMM: M=2048, N=9216, K=3072 -> 16x36 = 576 blocks of 128x256, BK=64
  gemm8p<0><<<16 * 36, 512, 0, stream>>>(Abf, Wqkv, HID, 36, QK, Vt, bv, nullptr, nullptr);

  // LN + rope: 2048*48*2 waves
  ln_rope_kernel<<<(SEQ * NH * 2) / 4, 256, 0, stream>>>(QK, bq, bk, gq, bgq, gk, bgk, freqs, Qh, Kh);

  // flash attention: 48 heads x 16 q-tiles of 128 rows, 512 threads
  fattn_kernel<<<NH * 16, 512, 0, stream>>>(Qh, Kh, Vt, ctx);

  // final GEMM: M=2048, N=3072, K=3072 -> 16x12 = 192 blocks of 128x256
  gemm8p<1><<<16 * 12, 512, 0, stream>>>(ctx, Wob, HID, 12, nullptr, nullptr, nullptr, out, bo);
}

// Round 20
// 400.912 us; speedup vs baseline: 1.0813x; 1.0008x over previous
//
#include <hip/hip_runtime.h>
#include <hip/hip_bf16.h>

typedef __attribute__((ext_vector_type(8))) short bf16x8;
typedef __attribute__((ext_vector_type(4))) float f32x4;
typedef unsigned int __attribute__((address_space(1))) as1_uint;
typedef unsigned int __attribute__((address_space(3))) as3_uint;

#define TXT 256
#define VIDN 1792
#define SEQ 2048
#define HID 3072
#define NH 48
#define HD 64
// attention scale 0.125 folded with log2(e) so softmax uses exp2 directly
#define QSCALE 0.18033688011112042f

__device__ __forceinline__ unsigned short f2bf(float f) {
  union { float f; unsigned int u; } x; x.f = f;
  unsigned int r = x.u + 0x7fffu + ((x.u >> 16) & 1u);
  return (unsigned short)(r >> 16);
}

__device__ __forceinline__ void gload16(const void* g, void* l) {
  __builtin_amdgcn_global_load_lds((const as1_uint*)g, (as3_uint*)l, 16, 0, 0);
}

// fenced raw barrier: no vmcnt drain (unlike __syncthreads), but compiler-fenced
__device__ __forceinline__ void fbar() {
  asm volatile("" ::: "memory");
  __builtin_amdgcn_s_barrier();
  asm volatile("" ::: "memory");
}

// combined + Wq + Wk + Wv + Wo -> bf16 in ONE launch
__global__ __launch_bounds__(256) void cvt5_kernel(
    const float* __restrict__ comb, const float* __restrict__ wq,
    const float* __restrict__ wk, const float* __restrict__ wv,
    const float* __restrict__ wo,
    unsigned short* __restrict__ abf, unsigned short* __restrict__ wqkv,
    unsigned short* __restrict__ wob) {
  const int CB = (SEQ * HID) / 1024;   // 6144 blocks for combined
  const int WB = (HID * HID) / 1024;   // 9216 blocks per weight
  int bid = blockIdx.x;
  const float* s; unsigned short* d; int r;
  if (bid < CB) { s = comb; d = abf; r = bid; }
  else {
    int q = bid - CB; int m = q / WB; r = q - m * WB;
    if (m < 3) { s = (m == 0) ? wq : (m == 1) ? wk : wv; d = wqkv + (size_t)m * HID * HID; }
    else { s = wo; d = wob; }
  }
  int i = (r * 256 + threadIdx.x) * 4;
  float4 v = *(const float4*)(s + i);
  ushort4 o;
  o.x = f2bf(v.x); o.y = f2bf(v.y); o.z = f2bf(v.z); o.w = f2bf(v.w);
  *(ushort4*)(d + i) = o;
}

// ---------- 128x256-tile BK=64 phase-interleaved bf16 GEMM (QKV) ----------
// QKV GEMM plateau: rounds 12-17 tried 5 structurally distinct schedules
// (2-phase x 3 tiles x {1,3} blk/CU, 4-phase BK=64) -> all ~930-960 TF,
// MfmaUtil 29-31%. Round-17 version kept; invariants in its header.
// Swizzle: byte' = byte ^ (((byte>>7)&7)<<4), rule-21 form.
// cols<6144 -> fp32 Cq[2048][6144]; cols>=6144 -> V: +bv, bf16,
// transposed Vt[col-6144][s].
__global__ __launch_bounds__(512) void gemm8p(
    const unsigned short* __restrict__ A,
    const unsigned short* __restrict__ Bt,
    int K, int ntn,
    float* __restrict__ Cq, unsigned short* __restrict__ Vt, const float* __restrict__ bv)
{
  __shared__ unsigned short lds[3 * 24576];  // 144 KiB
  const int tid = threadIdx.x;
  const int mt = blockIdx.x / ntn, nt = blockIdx.x % ntn;
  const int m0 = mt * 128, n0 = nt * 256;
  const int w = tid >> 6, lane = tid & 63, lr = lane & 15, lg = lane >> 4;
  const int wr = w >> 2, wc = w & 3;    // 2M x 4N wave grid; per-wave C: 64 x 64
  f32x4 acc[4][4] = {};
  const int NT = K >> 6;                // 48 K-tiles of 64

  // staging sources (pre-swizzled global), linear LDS dest offsets (bytes)
  const unsigned short *As0, *As1, *Bs0, *Bs1, *Bs2, *Bs3;
  int ao0, ao1, bb0, bb1, bb2, bb3;
  {
    int so, ss;
    so = tid * 16;          ss = so ^ (((so >> 7) & 7) << 4);
    ao0 = so; As0 = A + (size_t)(m0 + (ss >> 7)) * K + ((ss & 127) >> 1);
    so = (512 + tid) * 16;  ss = so ^ (((so >> 7) & 7) << 4);
    ao1 = so; As1 = A + (size_t)(m0 + (ss >> 7)) * K + ((ss & 127) >> 1);
    so = tid * 16;          ss = so ^ (((so >> 7) & 7) << 4);
    bb0 = so; Bs0 = Bt + (size_t)(n0 + (ss >> 7)) * K + ((ss & 127) >> 1);
    so = (512 + tid) * 16;  ss = so ^ (((so >> 7) & 7) << 4);
    bb1 = so; Bs1 = Bt + (size_t)(n0 + (ss >> 7)) * K + ((ss & 127) >> 1);
    so = (1024 + tid) * 16; ss = so ^ (((so >> 7) & 7) << 4);
    bb2 = so; Bs2 = Bt + (size_t)(n0 + (ss >> 7)) * K + ((ss & 127) >> 1);
    so = (1536 + tid) * 16; ss = so ^ (((so >> 7) & 7) << 4);
    bb3 = so; Bs3 = Bt + (size_t)(n0 + (ss >> 7)) * K + ((ss & 127) >> 1);
  }

  // swizzled ds_read element offsets: [k-half][fragment]
  int ra[2][4], rb[2][4];
#pragma unroll
  for (int h = 0; h < 2; ++h) {
#pragma unroll
    for (int f = 0; f < 4; ++f) {
      int r1 = wr * 64 + f * 16 + lr;
      ra[h][f] = (r1 * 64 + h * 32 + lg * 8) ^ ((r1 & 7) << 3);
      int r2 = wc * 64 + f * 16 + lr;
      rb[h][f] = (r2 * 64 + h * 32 + lg * 8) ^ ((r2 & 7) << 3);
    }
  }

#define STAGE_ALL(t)                                                           \
  {                                                                            \
    char* sb_ = (char*)lds + ((t) % 3) * 49152;                                \
    const int kk_ = (t) << 6;                                                  \
    gload16(As0 + kk_, sb_ + ao0);                                             \
    gload16(As1 + kk_, sb_ + ao1);                                             \
    gload16(Bs0 + kk_, sb_ + 16384 + bb0);                                     \
    gload16(Bs1 + kk_, sb_ + 16384 + bb1);                                     \
    gload16(Bs2 + kk_, sb_ + 16384 + bb2);                                     \
    gload16(Bs3 + kk_, sb_ + 16384 + bb3);                                     \
  }

#define MM8(N0, N1)                                                            \
  __builtin_amdgcn_s_setprio(1);                                               \
  acc[0][N0] = __builtin_amdgcn_mfma_f32_16x16x32_bf16(af0, bq0, acc[0][N0], 0, 0, 0); \
  acc[1][N0] = __builtin_amdgcn_mfma_f32_16x16x32_bf16(af1, bq0, acc[1][N0], 0, 0, 0); \
  acc[2][N0] = __builtin_amdgcn_mfma_f32_16x16x32_bf16(af2, bq0, acc[2][N0], 0, 0, 0); \
  acc[3][N0] = __builtin_amdgcn_mfma_f32_16x16x32_bf16(af3, bq0, acc[3][N0], 0, 0, 0); \
  acc[0][N1] = __builtin_amdgcn_mfma_f32_16x16x32_bf16(af0, bq1, acc[0][N1], 0, 0, 0); \
  acc[1][N1] = __builtin_amdgcn_mfma_f32_16x16x32_bf16(af1, bq1, acc[1][N1], 0, 0, 0); \
  acc[2][N1] = __builtin_amdgcn_mfma_f32_16x16x32_bf16(af2, bq1, acc[2][N1], 0, 0, 0); \
  acc[3][N1] = __builtin_amdgcn_mfma_f32_16x16x32_bf16(af3, bq1, acc[3][N1], 0, 0, 0); \
  __builtin_amdgcn_s_setprio(0);

#define ITER(t, SG, VMC)                                                       \
  {                                                                            \
    const unsigned short* lA = lds + ((t) % 3) * 24576;                        \
    const unsigned short* lB = lA + 8192;                                      \
    char* sb = (char*)lds + (((t) + 2) % 3) * 49152;                           \
    const int kk = ((t) + 2) << 6;                                             \
    bf16x8 af0, af1, af2, af3, bq0, bq1;                                       \
    af0 = *(const bf16x8*)&lA[ra[0][0]];                                       \
    af1 = *(const bf16x8*)&lA[ra[0][1]];                                       \
    af2 = *(const bf16x8*)&lA[ra[0][2]];                                       \
    af3 = *(const bf16x8*)&lA[ra[0][3]];                                       \
    bq0 = *(const bf16x8*)&lB[rb[0][0]];                                       \
    bq1 = *(const bf16x8*)&lB[rb[0][1]];                                       \
    if (SG) { gload16(As0 + kk, sb + ao0); gload16(As1 + kk, sb + ao1); }      \
    fbar();                                                                    \
    MM8(0, 1)                                                                  \
    fbar();                                                                    \
    bq0 = *(const bf16x8*)&lB[rb[0][2]];                                       \
    bq1 = *(const bf16x8*)&lB[rb[0][3]];                                       \
    if (SG) { gload16(Bs0 + kk, sb + 16384 + bb0);                             \
              gload16(Bs1 + kk, sb + 16384 + bb1); }                           \
    fbar();                                                                    \
    MM8(2, 3)                                                                  \
    fbar();                                                                    \
    af0 = *(const bf16x8*)&lA[ra[1][0]];                                       \
    af1 = *(const bf16x8*)&lA[ra[1][1]];                                       \
    af2 = *(const bf16x8*)&lA[ra[1][2]];                                       \
    af3 = *(const bf16x8*)&lA[ra[1][3]];                                       \
    bq0 = *(const bf16x8*)&lB[rb[1][0]];                                       \
    bq1 = *(const bf16x8*)&lB[rb[1][1]];                                       \
    if (SG) { gload16(Bs2 + kk, sb + 16384 + bb2);                             \
              gload16(Bs3 + kk, sb + 16384 + bb3); }                           \
    fbar();                                                                    \
    MM8(0, 1)                                                                  \
    fbar();                                                                    \
    bq0 = *(const bf16x8*)&lB[rb[1][2]];                                       \
    bq1 = *(const bf16x8*)&lB[rb[1][3]];                                       \
    VMC;                                                                       \
    fbar();                                                                    \
    MM8(2, 3)                                                                  \
    fbar();                                                                    \
  }

  STAGE_ALL(0);
  STAGE_ALL(1);
  asm volatile("s_waitcnt vmcnt(6)" ::: "memory");  // tile 0 drained, tile 1 in flight
  fbar();
  int t = 0;
  for (; t < NT - 2; ++t)
    ITER(t, 1, asm volatile("s_waitcnt vmcnt(6)" ::: "memory"));
  ITER(t, 0, asm volatile("s_waitcnt vmcnt(0)" ::: "memory"));
  ++t;
  ITER(t, 0, ((void)0));
#undef STAGE_ALL
#undef MM8
#undef ITER

  if (n0 < 6144) {
#pragma unroll
    for (int mf = 0; mf < 4; ++mf) {
      int row = m0 + wr * 64 + mf * 16 + lg * 4;
#pragma unroll
      for (int nf = 0; nf < 4; ++nf) {
        int col = n0 + wc * 64 + nf * 16 + lr;
#pragma unroll
        for (int j = 0; j < 4; ++j)
          Cq[(size_t)(row + j) * 6144 + col] = acc[mf][nf][j];
      }
    }
  } else {
#pragma unroll
    for (int mf = 0; mf < 4; ++mf) {
      int srow2 = m0 + wr * 64 + mf * 16 + lg * 4;
#pragma unroll
      for (int nf = 0; nf < 4; ++nf) {
        int n2 = n0 - 6144 + wc * 64 + nf * 16 + lr;
        float b = bv[n2];
        ushort4 pk;
        pk.x = f2bf(acc[mf][nf][0] + b);
        pk.y = f2bf(acc[mf][nf][1] + b);
        pk.z = f2bf(acc[mf][nf][2] + b);
        pk.w = f2bf(acc[mf][nf][3] + b);
        *(ushort4*)(Vt + (size_t)n2 * SEQ + srow2) = pk;
      }
    }
  }
}

// ------- 128x192-tile 2-phase bf16 GEMM (final): out = ctx*Wo^T + bo -------
// ROUND-20: fill fix. 128x256 gave 192 blocks on 256 CUs = 75% coverage.
// 128x192 -> grid 16x16 = EXACTLY 256 blocks = 1/CU, uniform single round.
// Proven round-13 2-phase template, parameters only: 256 thr, 4 waves (2M x 2N)
// of 64x96 (acc[4][6]=96 VGPR; launch_bounds(256,2) caps 256 - no spill),
// BK=32, slot = A 8KB + B 12KB, 3 slots = 60KB, 5 gloads/thread ->
//   { STAGE(t+2)=5; vmcnt(10); barrier; COMPUTE(t); barrier }, tails 5/0.
// Swizzle identical to round 13: byte' = byte ^ (((byte>>7)&3)<<4).
// fp32 out, rows permuted vid-first.
__global__ __launch_bounds__(256, 2) void gemmF(
    const unsigned short* __restrict__ A,
    const unsigned short* __restrict__ Bt,
    float* __restrict__ Cout, const float* __restrict__ bo)
{
  __shared__ unsigned short lds[3 * 10240];  // 3 x (A 8KB + B 12KB) = 60 KiB
  const int K = HID;
  const int tid = threadIdx.x;
  const int mt = blockIdx.x >> 4, nt = blockIdx.x & 15;
  const int m0 = mt * 128, n0 = nt * 192;
  const int w = tid >> 6, lane = tid & 63, lr = lane & 15, lg = lane >> 4;
  const int wr = w >> 1, wc = w & 1;    // 2M x 2N; per-wave C: 64 x 96
  f32x4 acc[4][6] = {};
  const int NT = K >> 5;                // 96 K-tiles

  // staging: linear LDS dest, pre-swizzled global source
  const unsigned short* Asrc[2];
  const unsigned short* Bsrc[3];
  int aol[2], bol[3];
#pragma unroll
  for (int c = 0; c < 2; ++c) {
    int so = (c * 256 + tid) * 16;
    aol[c] = so;
    int ss = so ^ (((so >> 7) & 3) << 4);
    Asrc[c] = A + (size_t)(m0 + (ss >> 6)) * K + ((ss & 63) >> 1);
  }
#pragma unroll
  for (int c = 0; c < 3; ++c) {
    int so = (c * 256 + tid) * 16;
    bol[c] = so;
    int ss = so ^ (((so >> 7) & 3) << 4);
    Bsrc[c] = Bt + (size_t)(n0 + (ss >> 6)) * K + ((ss & 63) >> 1);
  }

  // swizzled ds_read element offsets
  int aoff[4], boff[6];
#pragma unroll
  for (int mf = 0; mf < 4; ++mf) {
    int arow = wr * 64 + mf * 16 + lr;
    aoff[mf] = arow * 32 + (lg ^ ((arow >> 1) & 3)) * 8;
  }
#pragma unroll
  for (int nf = 0; nf < 6; ++nf) {
    int brow = wc * 96 + nf * 16 + lr;
    boff[nf] = brow * 32 + (lg ^ ((brow >> 1) & 3)) * 8;
  }

#define FSTG(t)                                                                \
  {                                                                            \
    char* base_ = (char*)lds + ((t) % 3) * 20480;                              \
    const int k0_ = (t) << 5;                                                  \
    gload16(Asrc[0] + k0_, base_ + aol[0]);                                    \
    gload16(Asrc[1] + k0_, base_ + aol[1]);                                    \
    gload16(Bsrc[0] + k0_, base_ + 8192 + bol[0]);                             \
    gload16(Bsrc[1] + k0_, base_ + 8192 + bol[1]);                             \
    gload16(Bsrc[2] + k0_, base_ + 8192 + bol[2]);                             \
  }

#define FCMP(t)                                                                \
  {                                                                            \
    const unsigned short* lA = lds + ((t) % 3) * 10240;                        \
    const unsigned short* lB = lA + 4096;                                      \
    bf16x8 bfr[6];                                                             \
    _Pragma("unroll")                                                          \
    for (int nf = 0; nf < 6; ++nf)                                             \
      bfr[nf] = *(const bf16x8*)&lB[boff[nf]];                                 \
    __builtin_amdgcn_s_setprio(1);                                             \
    _Pragma("unroll")                                                          \
    for (int mf = 0; mf < 4; ++mf) {                                           \
      bf16x8 af = *(const bf16x8*)&lA[aoff[mf]];                               \
      _Pragma("unroll")                                                        \
      for (int nf = 0; nf < 6; ++nf)                                           \
        acc[mf][nf] = __builtin_amdgcn_mfma_f32_16x16x32_bf16(af, bfr[nf], acc[mf][nf], 0, 0, 0); \
    }                                                                          \
    __builtin_amdgcn_s_setprio(0);                                             \
  }

  FSTG(0); FSTG(1);
  int t = 0;
  for (; t < NT - 2; ++t) {
    FSTG(t + 2);
    asm volatile("s_waitcnt vmcnt(10)" ::: "memory");
    fbar();           // all waves' tile-t writes now in LDS
    FCMP(t);
    fbar();           // all waves done reading slot t%3 before it is re-staged
  }
  asm volatile("s_waitcnt vmcnt(5)" ::: "memory");
  fbar();
  FCMP(t); ++t;
  fbar();
  asm volatile("s_waitcnt vmcnt(0)" ::: "memory");
  fbar();
  FCMP(t);
#undef FSTG
#undef FCMP

#pragma unroll
  for (int mf = 0; mf < 4; ++mf) {
    int row = m0 + wr * 64 + mf * 16 + lg * 4;
#pragma unroll
    for (int nf = 0; nf < 6; ++nf) {
      int col = n0 + wc * 96 + nf * 16 + lr;
      float b = bo[col];
#pragma unroll
      for (int j = 0; j < 4; ++j) {
        int s = row + j;
        int orow = (s >= TXT) ? (s - TXT) : (VIDN + s);
        Cout[(size_t)orow * HID + col] = acc[mf][nf][j] + b;
      }
    }
  }
}

// ---------------- LayerNorm + head-indexed RoPE ----------------
// one wave per (s, h, qk): LN over 64 dims, rope for s>=TXT, Q scaled by QSCALE.
__global__ __launch_bounds__(256) void ln_rope_kernel(
    const float* __restrict__ QK,
    const float* __restrict__ bq, const float* __restrict__ bk,
    const float* __restrict__ gq, const float* __restrict__ bgq,
    const float* __restrict__ gk, const float* __restrict__ bgk,
    const float* __restrict__ freqs,
    unsigned short* __restrict__ Qh, unsigned short* __restrict__ Kh)
{
  int wid = blockIdx.x * 4 + (threadIdx.x >> 6);
  int lane = threadIdx.x & 63;
  int s = wid / 96;
  int rem = wid - s * 96;
  int h = rem >> 1, qk = rem & 1;
  int col = h * 64 + lane;
  float x = QK[(size_t)s * 6144 + qk * 3072 + col] + (qk ? bk[col] : bq[col]);
  float m = x;
#pragma unroll
  for (int msk = 1; msk < 64; msk <<= 1) m += __shfl_xor(m, msk);
  float mu = m * (1.0f / 64.0f);
  float xc = x - mu;
  float v = xc * xc;
#pragma unroll
  for (int msk = 1; msk < 64; msk <<= 1) v += __shfl_xor(v, msk);
  float rstd = rsqrtf(v * (1.0f / 64.0f) + 1e-5f);
  float y = xc * rstd * (qk ? gk[lane] : gq[lane]) + (qk ? bgk[lane] : bgq[lane]);
  if (s >= TXT) {
    // out[2d+j] = f[h][d][j][0]*x[2d] + f[h][d][j][1]*x[2d+1]; freqs head-indexed
    float p = __shfl_xor(y, 1);
    float xe = (lane & 1) ? p : y;
    float xo = (lane & 1) ? y : p;
    int base = h * 128 + (lane >> 1) * 4 + (lane & 1) * 2;
    y = freqs[base] * xe + freqs[base + 1] * xo;
  }
  if (!qk) y *= QSCALE;  // fold attention scale (and log2e for exp2-softmax) into Q
  (qk ? Kh : Qh)[((size_t)h * SEQ + s) * 64 + lane] = f2bf(y);
}

// ---------------- flash attention (swapped-QK^T softmax) ----------------
// ROUND-17 version (best measured ~90 us; QBLK=256 regressed: q-groups
// serialized through shared pl slice + VGPR pressure).
// grid: h * 16 q-tiles; 8 waves x 16 q-rows (QBLK=128); BKV=64; D=64.
// Double-buffered K/V staging with counted vmcnt: { FSTAGE(t+1)=2 gloads;
// vmcnt(2); fbar; compute(t); fbar }. Q-loads issue BEFORE FSTAGE(0).
// St = mfma(K,Q) puts q on lane&15: row-reduce = 15 in-reg ops + 2 shuffles.
__global__ __launch_bounds__(512) void fattn_kernel(
    const unsigned short* __restrict__ Qh, const unsigned short* __restrict__ Kh,
    const unsigned short* __restrict__ Vt, unsigned short* __restrict__ ctx)
{
  __shared__ unsigned short kt[2][2][64][32];  // [slot][half][row][col]
  __shared__ unsigned short vt[2][2][64][32];
  __shared__ unsigned short pl[8][16][72];
  const int h = blockIdx.x >> 4;
  const int q0 = (blockIdx.x & 15) * 128;
  const int tid = threadIdx.x, w = tid >> 6, lane = tid & 63, lr = lane & 15, lg = lane >> 4;

  bf16x8 qf0, qf1;
  {
    const unsigned short* qp = Qh + ((size_t)h * SEQ + q0 + w * 16 + lr) * 64 + lg * 8;
    qf0 = *(const bf16x8*)qp;
    qf1 = *(const bf16x8*)(qp + 32);
  }
  f32x4 oacc[4] = {};
  float mrun = -1e30f, lrun = 0.f;   // this lane's q-row = q0 + w*16 + lr

  // per-thread staging addresses (fixed row/half/col; kv advances the source)
  const int soff = tid * 16;
  const int shalf = soff >> 12;
  const int srem = soff & 4095;
  const int srow = srem >> 6, scb = srem & 63;
  const unsigned short* Ksrc = Kh + ((size_t)h * SEQ + srow) * 64 + shalf * 32 + (scb >> 1);
  const unsigned short* Vsrc = Vt + ((size_t)(h * 64 + srow)) * SEQ + shalf * 32 + (scb >> 1);

#define FSTAGE(t)                                                              \
  {                                                                            \
    const int sl_ = (t) & 1;                                                   \
    const int kv0_ = (t) << 6;                                                 \
    gload16(Ksrc + (size_t)kv0_ * 64, (char*)kt + sl_ * 8192 + soff);          \
    gload16(Vsrc + kv0_, (char*)vt + sl_ * 8192 + soff);                       \
  }

  FSTAGE(0);
  for (int t = 0; t < 32; ++t) {
    const int sl = t & 1;
    if (t < 31) {
      FSTAGE(t + 1);
      asm volatile("s_waitcnt vmcnt(2)" ::: "memory");
    } else {
      asm volatile("s_waitcnt vmcnt(0)" ::: "memory");
    }
    fbar();   // all waves' tile-t K/V writes now in LDS

    // St[kv][q]: sacc[nf][r] = S[q = lr][kv = t*64 + nf*16 + lg*4 + r]
    f32x4 sacc[4] = {};
    __builtin_amdgcn_s_setprio(1);
#pragma unroll
    for (int nf = 0; nf < 4; ++nf) {
      bf16x8 a0 = *(const bf16x8*)&kt[sl][0][nf * 16 + lr][lg * 8];
      bf16x8 a1 = *(const bf16x8*)&kt[sl][1][nf * 16 + lr][lg * 8];
      sacc[nf] = __builtin_amdgcn_mfma_f32_16x16x32_bf16(a0, qf0, sacc[nf], 0, 0, 0);
      sacc[nf] = __builtin_amdgcn_mfma_f32_16x16x32_bf16(a1, qf1, sacc[nf], 0, 0, 0);
    }
    __builtin_amdgcn_s_setprio(0);

    // tile max over the 16 in-register kv values, then xor16/xor32
    float mx;
    {
      float t0 = fmaxf(fmaxf(sacc[0][0], sacc[0][1]), fmaxf(sacc[0][2], sacc[0][3]));
      float t1 = fmaxf(fmaxf(sacc[1][0], sacc[1][1]), fmaxf(sacc[1][2], sacc[1][3]));
      float t2 = fmaxf(fmaxf(sacc[2][0], sacc[2][1]), fmaxf(sacc[2][2], sacc[2][3]));
      float t3 = fmaxf(fmaxf(sacc[3][0], sacc[3][1]), fmaxf(sacc[3][2], sacc[3][3]));
      mx = fmaxf(fmaxf(t0, t1), fmaxf(t2, t3));
    }
    mx = fmaxf(mx, __shfl_xor(mx, 16));
    mx = fmaxf(mx, __shfl_xor(mx, 32));

    // defer-max (log2 units): only rescale when max grew past threshold
    if (!__all(mx <= mrun + 8.0f)) {
      float mn = fmaxf(mrun, mx);
      float corr = exp2f(mrun - mn);
      lrun *= corr;
      mrun = mn;
      float c0 = __shfl(corr, lg * 4 + 0);
      float c1 = __shfl(corr, lg * 4 + 1);
      float c2 = __shfl(corr, lg * 4 + 2);
      float c3 = __shfl(corr, lg * 4 + 3);
#pragma unroll
      for (int df = 0; df < 4; ++df) {
        oacc[df][0] *= c0; oacc[df][1] *= c1;
        oacc[df][2] *= c2; oacc[df][3] *= c3;
      }
    }

    // P = exp2(S - mrun); row-sum; pack to bf16 and write P[q][kv] as b64
    float pr[4][4];
#pragma unroll
    for (int nf = 0; nf < 4; ++nf)
#pragma unroll
      for (int r = 0; r < 4; ++r)
        pr[nf][r] = exp2f(sacc[nf][r] - mrun);
    float rs;
    {
      float s0 = (pr[0][0] + pr[0][1]) + (pr[0][2] + pr[0][3]);
      float s1 = (pr[1][0] + pr[1][1]) + (pr[1][2] + pr[1][3]);
      float s2 = (pr[2][0] + pr[2][1]) + (pr[2][2] + pr[2][3]);
      float s3 = (pr[3][0] + pr[3][1]) + (pr[3][2] + pr[3][3]);
      rs = (s0 + s1) + (s2 + s3);
    }
    rs += __shfl_xor(rs, 16);
    rs += __shfl_xor(rs, 32);
    lrun += rs;

#pragma unroll
    for (int nf = 0; nf < 4; ++nf) {
      union { __hip_bfloat162 h; unsigned int u; } c0, c1;
      c0.h = __float22bfloat162_rn(make_float2(pr[nf][0], pr[nf][1]));
      c1.h = __float22bfloat162_rn(make_float2(pr[nf][2], pr[nf][3]));
      uint2 pw; pw.x = c0.u; pw.y = c1.u;
      *(uint2*)&pl[w][lr][nf * 16 + lg * 4] = pw;
    }
    // no barrier: pl slice is per-wave; lgkmcnt orders write->read

    bf16x8 pa0 = *(const bf16x8*)&pl[w][lr][lg * 8];
    bf16x8 pa1 = *(const bf16x8*)&pl[w][lr][32 + lg * 8];
    __builtin_amdgcn_s_setprio(1);
#pragma unroll
    for (int df = 0; df < 4; ++df) {
      bf16x8 v0 = *(const bf16x8*)&vt[sl][0][df * 16 + lr][lg * 8];
      bf16x8 v1 = *(const bf16x8*)&vt[sl][1][df * 16 + lr][lg * 8];
      oacc[df] = __builtin_amdgcn_mfma_f32_16x16x32_bf16(pa0, v0, oacc[df], 0, 0, 0);
      oacc[df] = __builtin_amdgcn_mfma_f32_16x16x32_bf16(pa1, v1, oacc[df], 0, 0, 0);
    }
    __builtin_amdgcn_s_setprio(0);

    fbar();   // all waves done reading slot sl before it is re-staged
  }
#undef FSTAGE

  // epilogue: move 1/lrun (at q=lane&15 layout) to C-layout rows via shfl
  float linv = 1.0f / lrun;
  float i0 = __shfl(linv, lg * 4 + 0);
  float i1 = __shfl(linv, lg * 4 + 1);
  float i2 = __shfl(linv, lg * 4 + 2);
  float i3 = __shfl(linv, lg * 4 + 3);
#pragma unroll
  for (int df = 0; df < 4; ++df) {
    int s = q0 + w * 16 + lg * 4;
    int dcol = h * 64 + df * 16 + lr;
    ctx[(size_t)(s + 0) * HID + dcol] = f2bf(oacc[df][0] * i0);
    ctx[(size_t)(s + 1) * HID + dcol] = f2bf(oacc[df][1] * i1);
    ctx[(size_t)(s + 2) * HID + dcol] = f2bf(oacc[df][2] * i2);
    ctx[(size_t)(s + 3) * HID + dcol] = f2bf(oacc[df][3] * i3);
  }
}

extern "C" void kernel_launch(void* const* d_in, const int* in_sizes, int n_in,
                              void* d_out, int out_size, void* d_ws, size_t ws_size,
                              hipStream_t stream) {
  const float* combined = (const float*)d_in[0];
  const float* freqs    = (const float*)d_in[1];
  const float* Wq  = (const float*)d_in[2];
  const float* bq  = (const float*)d_in[3];
  const float* Wk  = (const float*)d_in[4];
  const float* bk  = (const float*)d_in[5];
  const float* Wv  = (const float*)d_in[6];
  const float* bv  = (const float*)d_in[7];
  const float* Wo  = (const float*)d_in[8];
  const float* bo  = (const float*)d_in[9];
  const float* gq  = (const float*)d_in[10];
  const float* bgq = (const float*)d_in[11];
  const float* gk  = (const float*)d_in[12];
  const float* bgk = (const float*)d_in[13];
  float* out = (float*)d_out;  // reference output dtype is float32

  char* ws = (char*)d_ws;
  unsigned short* Abf  = (unsigned short*)ws; ws += (size_t)SEQ * HID * 2;    // reused as ctx
  unsigned short* Wqkv = (unsigned short*)ws; ws += (size_t)3 * HID * HID * 2;
  float*          QK   = (float*)ws;          ws += (size_t)SEQ * 6144 * 4;
  unsigned short* Qh   = (unsigned short*)ws; ws += (size_t)NH * SEQ * HD * 2;
  unsigned short* Kh   = (unsigned short*)ws; ws += (size_t)NH * SEQ * HD * 2;
  unsigned short* Vt   = (unsigned short*)ws; ws += (size_t)NH * HD * SEQ * 2;
  unsigned short* Wob  = (unsigned short*)ws; ws += (size_t)HID * HID * 2;    // 176 MB total < 189 MB proven
  unsigned short* ctx  = Abf;                   // alias: Abf dead after QKV GEMM

  // combined + Wq + Wk + Wv + Wo -> bf16 in one launch
  cvt5_kernel<<<(SEQ * HID) / 1024 + 4 * (HID * HID) / 1024, 256, 0, stream>>>(
      combined, Wq, Wk, Wv, Wo, Abf, Wqkv, Wob);

  // QKV GEMM: M=2048, N=9216, K=3072 -> 16x36 = 576 blocks of 128x256, BK=64
  gemm8p<<<16 * 36, 512, 0, stream>>>(Abf, Wqkv, HID, 36, QK, Vt, bv);

  // LN + rope: 2048*48*2 waves
  ln_rope_kernel<<<(SEQ * NH * 2) / 4, 256, 0, stream>>>(QK, bq, bk, gq, bgq, gk, bgk, freqs, Qh, Kh);

  // flash attention: 48 heads x 16 q-tiles of 128 rows, 512 threads
  fattn_kernel<<<NH * 16, 512, 0, stream>>>(Qh, Kh, Vt, ctx);

  // final GEMM: M=2048, N=3072, K=3072 -> 16x16 = 256 blocks of 128x192 (1/CU)
  gemmF<<<16 * 16, 256, 0, stream>>>(ctx, Wob, out, bo);
}

// Round 21
// 394.898 us; speedup vs baseline: 1.0978x; 1.0152x over previous
//
#include <hip/hip_runtime.h>
#include <hip/hip_bf16.h>

typedef __attribute__((ext_vector_type(8))) short bf16x8;
typedef __attribute__((ext_vector_type(4))) float f32x4;
typedef unsigned int __attribute__((address_space(1))) as1_uint;
typedef unsigned int __attribute__((address_space(3))) as3_uint;

#define TXT 256
#define VIDN 1792
#define SEQ 2048
#define HID 3072
#define NH 48
#define HD 64
// attention scale 0.125 folded with log2(e) so softmax uses exp2 directly
#define QSCALE 0.18033688011112042f

__device__ __forceinline__ unsigned short f2bf(float f) {
  union { float f; unsigned int u; } x; x.f = f;
  unsigned int r = x.u + 0x7fffu + ((x.u >> 16) & 1u);
  return (unsigned short)(r >> 16);
}

__device__ __forceinline__ float bf2f(unsigned short b) {
  union { unsigned int u; float f; } x; x.u = ((unsigned int)b) << 16;
  return x.f;
}

__device__ __forceinline__ void gload16(const void* g, void* l) {
  __builtin_amdgcn_global_load_lds((const as1_uint*)g, (as3_uint*)l, 16, 0, 0);
}

// fenced raw barrier: no vmcnt drain (unlike __syncthreads), but compiler-fenced
__device__ __forceinline__ void fbar() {
  asm volatile("" ::: "memory");
  __builtin_amdgcn_s_barrier();
  asm volatile("" ::: "memory");
}

// combined + Wq + Wk + Wv + Wo -> bf16 in ONE launch
__global__ __launch_bounds__(256) void cvt5_kernel(
    const float* __restrict__ comb, const float* __restrict__ wq,
    const float* __restrict__ wk, const float* __restrict__ wv,
    const float* __restrict__ wo,
    unsigned short* __restrict__ abf, unsigned short* __restrict__ wqkv,
    unsigned short* __restrict__ wob) {
  const int CB = (SEQ * HID) / 1024;   // 6144 blocks for combined
  const int WB = (HID * HID) / 1024;   // 9216 blocks per weight
  int bid = blockIdx.x;
  const float* s; unsigned short* d; int r;
  if (bid < CB) { s = comb; d = abf; r = bid; }
  else {
    int q = bid - CB; int m = q / WB; r = q - m * WB;
    if (m < 3) { s = (m == 0) ? wq : (m == 1) ? wk : wv; d = wqkv + (size_t)m * HID * HID; }
    else { s = wo; d = wob; }
  }
  int i = (r * 256 + threadIdx.x) * 4;
  float4 v = *(const float4*)(s + i);
  ushort4 o;
  o.x = f2bf(v.x); o.y = f2bf(v.y); o.z = f2bf(v.z); o.w = f2bf(v.w);
  *(ushort4*)(d + i) = o;
}

// ---------- 128x256-tile BK=64 phase-interleaved bf16 GEMM (QKV) ----------
// QKV GEMM plateau: rounds 12-20 tried 6 structurally distinct schedules
// (2-phase x 4 tiles x {1,2,3} blk/CU, 4-phase BK=64) -> all ~930-960 TF
// resident / ~700 TF avg, MfmaUtil 29-31%. Round-17 version kept.
// Swizzle: byte' = byte ^ (((byte>>7)&7)<<4), rule-21 form.
// ROUND-21: Q/K intermediate written as BF16 (was fp32): downstream LN only
// needs ~bf16 input precision; saves 25 MB write + 25 MB read of HBM.
// cols<6144 -> bf16 Cq[2048][6144]; cols>=6144 -> V: +bv, bf16,
// transposed Vt[col-6144][s].
__global__ __launch_bounds__(512) void gemm8p(
    const unsigned short* __restrict__ A,
    const unsigned short* __restrict__ Bt,
    int K, int ntn,
    unsigned short* __restrict__ Cq, unsigned short* __restrict__ Vt,
    const float* __restrict__ bv)
{
  __shared__ unsigned short lds[3 * 24576];  // 144 KiB
  const int tid = threadIdx.x;
  const int mt = blockIdx.x / ntn, nt = blockIdx.x % ntn;
  const int m0 = mt * 128, n0 = nt * 256;
  const int w = tid >> 6, lane = tid & 63, lr = lane & 15, lg = lane >> 4;
  const int wr = w >> 2, wc = w & 3;    // 2M x 4N wave grid; per-wave C: 64 x 64
  f32x4 acc[4][4] = {};
  const int NT = K >> 6;                // 48 K-tiles of 64

  // staging sources (pre-swizzled global), linear LDS dest offsets (bytes)
  const unsigned short *As0, *As1, *Bs0, *Bs1, *Bs2, *Bs3;
  int ao0, ao1, bb0, bb1, bb2, bb3;
  {
    int so, ss;
    so = tid * 16;          ss = so ^ (((so >> 7) & 7) << 4);
    ao0 = so; As0 = A + (size_t)(m0 + (ss >> 7)) * K + ((ss & 127) >> 1);
    so = (512 + tid) * 16;  ss = so ^ (((so >> 7) & 7) << 4);
    ao1 = so; As1 = A + (size_t)(m0 + (ss >> 7)) * K + ((ss & 127) >> 1);
    so = tid * 16;          ss = so ^ (((so >> 7) & 7) << 4);
    bb0 = so; Bs0 = Bt + (size_t)(n0 + (ss >> 7)) * K + ((ss & 127) >> 1);
    so = (512 + tid) * 16;  ss = so ^ (((so >> 7) & 7) << 4);
    bb1 = so; Bs1 = Bt + (size_t)(n0 + (ss >> 7)) * K + ((ss & 127) >> 1);
    so = (1024 + tid) * 16; ss = so ^ (((so >> 7) & 7) << 4);
    bb2 = so; Bs2 = Bt + (size_t)(n0 + (ss >> 7)) * K + ((ss & 127) >> 1);
    so = (1536 + tid) * 16; ss = so ^ (((so >> 7) & 7) << 4);
    bb3 = so; Bs3 = Bt + (size_t)(n0 + (ss >> 7)) * K + ((ss & 127) >> 1);
  }

  // swizzled ds_read element offsets: [k-half][fragment]
  int ra[2][4], rb[2][4];
#pragma unroll
  for (int h = 0; h < 2; ++h) {
#pragma unroll
    for (int f = 0; f < 4; ++f) {
      int r1 = wr * 64 + f * 16 + lr;
      ra[h][f] = (r1 * 64 + h * 32 + lg * 8) ^ ((r1 & 7) << 3);
      int r2 = wc * 64 + f * 16 + lr;
      rb[h][f] = (r2 * 64 + h * 32 + lg * 8) ^ ((r2 & 7) << 3);
    }
  }

#define STAGE_ALL(t)                                                           \
  {                                                                            \
    char* sb_ = (char*)lds + ((t) % 3) * 49152;                                \
    const int kk_ = (t) << 6;                                                  \
    gload16(As0 + kk_, sb_ + ao0);                                             \
    gload16(As1 + kk_, sb_ + ao1);                                             \
    gload16(Bs0 + kk_, sb_ + 16384 + bb0);                                     \
    gload16(Bs1 + kk_, sb_ + 16384 + bb1);                                     \
    gload16(Bs2 + kk_, sb_ + 16384 + bb2);                                     \
    gload16(Bs3 + kk_, sb_ + 16384 + bb3);                                     \
  }

#define MM8(N0, N1)                                                            \
  __builtin_amdgcn_s_setprio(1);                                               \
  acc[0][N0] = __builtin_amdgcn_mfma_f32_16x16x32_bf16(af0, bq0, acc[0][N0], 0, 0, 0); \
  acc[1][N0] = __builtin_amdgcn_mfma_f32_16x16x32_bf16(af1, bq0, acc[1][N0], 0, 0, 0); \
  acc[2][N0] = __builtin_amdgcn_mfma_f32_16x16x32_bf16(af2, bq0, acc[2][N0], 0, 0, 0); \
  acc[3][N0] = __builtin_amdgcn_mfma_f32_16x16x32_bf16(af3, bq0, acc[3][N0], 0, 0, 0); \
  acc[0][N1] = __builtin_amdgcn_mfma_f32_16x16x32_bf16(af0, bq1, acc[0][N1], 0, 0, 0); \
  acc[1][N1] = __builtin_amdgcn_mfma_f32_16x16x32_bf16(af1, bq1, acc[1][N1], 0, 0, 0); \
  acc[2][N1] = __builtin_amdgcn_mfma_f32_16x16x32_bf16(af2, bq1, acc[2][N1], 0, 0, 0); \
  acc[3][N1] = __builtin_amdgcn_mfma_f32_16x16x32_bf16(af3, bq1, acc[3][N1], 0, 0, 0); \
  __builtin_amdgcn_s_setprio(0);

#define ITER(t, SG, VMC)                                                       \
  {                                                                            \
    const unsigned short* lA = lds + ((t) % 3) * 24576;                        \
    const unsigned short* lB = lA + 8192;                                      \
    char* sb = (char*)lds + (((t) + 2) % 3) * 49152;                           \
    const int kk = ((t) + 2) << 6;                                             \
    bf16x8 af0, af1, af2, af3, bq0, bq1;                                       \
    af0 = *(const bf16x8*)&lA[ra[0][0]];                                       \
    af1 = *(const bf16x8*)&lA[ra[0][1]];                                       \
    af2 = *(const bf16x8*)&lA[ra[0][2]];                                       \
    af3 = *(const bf16x8*)&lA[ra[0][3]];                                       \
    bq0 = *(const bf16x8*)&lB[rb[0][0]];                                       \
    bq1 = *(const bf16x8*)&lB[rb[0][1]];                                       \
    if (SG) { gload16(As0 + kk, sb + ao0); gload16(As1 + kk, sb + ao1); }      \
    fbar();                                                                    \
    MM8(0, 1)                                                                  \
    fbar();                                                                    \
    bq0 = *(const bf16x8*)&lB[rb[0][2]];                                       \
    bq1 = *(const bf16x8*)&lB[rb[0][3]];                                       \
    if (SG) { gload16(Bs0 + kk, sb + 16384 + bb0);                             \
              gload16(Bs1 + kk, sb + 16384 + bb1); }                           \
    fbar();                                                                    \
    MM8(2, 3)                                                                  \
    fbar();                                                                    \
    af0 = *(const bf16x8*)&lA[ra[1][0]];                                       \
    af1 = *(const bf16x8*)&lA[ra[1][1]];                                       \
    af2 = *(const bf16x8*)&lA[ra[1][2]];                                       \
    af3 = *(const bf16x8*)&lA[ra[1][3]];                                       \
    bq0 = *(const bf16x8*)&lB[rb[1][0]];                                       \
    bq1 = *(const bf16x8*)&lB[rb[1][1]];                                       \
    if (SG) { gload16(Bs2 + kk, sb + 16384 + bb2);                             \
              gload16(Bs3 + kk, sb + 16384 + bb3); }                           \
    fbar();                                                                    \
    MM8(0, 1)                                                                  \
    fbar();                                                                    \
    bq0 = *(const bf16x8*)&lB[rb[1][2]];                                       \
    bq1 = *(const bf16x8*)&lB[rb[1][3]];                                       \
    VMC;                                                                       \
    fbar();                                                                    \
    MM8(2, 3)                                                                  \
    fbar();                                                                    \
  }

  STAGE_ALL(0);
  STAGE_ALL(1);
  asm volatile("s_waitcnt vmcnt(6)" ::: "memory");  // tile 0 drained, tile 1 in flight
  fbar();
  int t = 0;
  for (; t < NT - 2; ++t)
    ITER(t, 1, asm volatile("s_waitcnt vmcnt(6)" ::: "memory"));
  ITER(t, 0, asm volatile("s_waitcnt vmcnt(0)" ::: "memory"));
  ++t;
  ITER(t, 0, ((void)0));
#undef STAGE_ALL
#undef MM8
#undef ITER

  if (n0 < 6144) {
#pragma unroll
    for (int mf = 0; mf < 4; ++mf) {
      int row = m0 + wr * 64 + mf * 16 + lg * 4;
#pragma unroll
      for (int nf = 0; nf < 4; ++nf) {
        int col = n0 + wc * 64 + nf * 16 + lr;
#pragma unroll
        for (int j = 0; j < 4; ++j)
          Cq[(size_t)(row + j) * 6144 + col] = f2bf(acc[mf][nf][j]);
      }
    }
  } else {
#pragma unroll
    for (int mf = 0; mf < 4; ++mf) {
      int srow2 = m0 + wr * 64 + mf * 16 + lg * 4;
#pragma unroll
      for (int nf = 0; nf < 4; ++nf) {
        int n2 = n0 - 6144 + wc * 64 + nf * 16 + lr;
        float b = bv[n2];
        ushort4 pk;
        pk.x = f2bf(acc[mf][nf][0] + b);
        pk.y = f2bf(acc[mf][nf][1] + b);
        pk.z = f2bf(acc[mf][nf][2] + b);
        pk.w = f2bf(acc[mf][nf][3] + b);
        *(ushort4*)(Vt + (size_t)n2 * SEQ + srow2) = pk;
      }
    }
  }
}

// ------- 128x192-tile 2-phase bf16 GEMM (final): out = ctx*Wo^T + bo -------
// Round-20 version: grid 16x16 = 256 blocks = 1/CU. Proven round-13 2-phase
// template; swizzle byte' = byte ^ (((byte>>7)&3)<<4). fp32 out, vid-first rows.
__global__ __launch_bounds__(256, 2) void gemmF(
    const unsigned short* __restrict__ A,
    const unsigned short* __restrict__ Bt,
    float* __restrict__ Cout, const float* __restrict__ bo)
{
  __shared__ unsigned short lds[3 * 10240];  // 3 x (A 8KB + B 12KB) = 60 KiB
  const int K = HID;
  const int tid = threadIdx.x;
  const int mt = blockIdx.x >> 4, nt = blockIdx.x & 15;
  const int m0 = mt * 128, n0 = nt * 192;
  const int w = tid >> 6, lane = tid & 63, lr = lane & 15, lg = lane >> 4;
  const int wr = w >> 1, wc = w & 1;    // 2M x 2N; per-wave C: 64 x 96
  f32x4 acc[4][6] = {};
  const int NT = K >> 5;                // 96 K-tiles

  // staging: linear LDS dest, pre-swizzled global source
  const unsigned short* Asrc[2];
  const unsigned short* Bsrc[3];
  int aol[2], bol[3];
#pragma unroll
  for (int c = 0; c < 2; ++c) {
    int so = (c * 256 + tid) * 16;
    aol[c] = so;
    int ss = so ^ (((so >> 7) & 3) << 4);
    Asrc[c] = A + (size_t)(m0 + (ss >> 6)) * K + ((ss & 63) >> 1);
  }
#pragma unroll
  for (int c = 0; c < 3; ++c) {
    int so = (c * 256 + tid) * 16;
    bol[c] = so;
    int ss = so ^ (((so >> 7) & 3) << 4);
    Bsrc[c] = Bt + (size_t)(n0 + (ss >> 6)) * K + ((ss & 63) >> 1);
  }

  // swizzled ds_read element offsets
  int aoff[4], boff[6];
#pragma unroll
  for (int mf = 0; mf < 4; ++mf) {
    int arow = wr * 64 + mf * 16 + lr;
    aoff[mf] = arow * 32 + (lg ^ ((arow >> 1) & 3)) * 8;
  }
#pragma unroll
  for (int nf = 0; nf < 6; ++nf) {
    int brow = wc * 96 + nf * 16 + lr;
    boff[nf] = brow * 32 + (lg ^ ((brow >> 1) & 3)) * 8;
  }

#define FSTG(t)                                                                \
  {                                                                            \
    char* base_ = (char*)lds + ((t) % 3) * 20480;                              \
    const int k0_ = (t) << 5;                                                  \
    gload16(Asrc[0] + k0_, base_ + aol[0]);                                    \
    gload16(Asrc[1] + k0_, base_ + aol[1]);                                    \
    gload16(Bsrc[0] + k0_, base_ + 8192 + bol[0]);                             \
    gload16(Bsrc[1] + k0_, base_ + 8192 + bol[1]);                             \
    gload16(Bsrc[2] + k0_, base_ + 8192 + bol[2]);                             \
  }

#define FCMP(t)                                                                \
  {                                                                            \
    const unsigned short* lA = lds + ((t) % 3) * 10240;                        \
    const unsigned short* lB = lA + 4096;                                      \
    bf16x8 bfr[6];                                                             \
    _Pragma("unroll")                                                          \
    for (int nf = 0; nf < 6; ++nf)                                             \
      bfr[nf] = *(const bf16x8*)&lB[boff[nf]];                                 \
    __builtin_amdgcn_s_setprio(1);                                             \
    _Pragma("unroll")                                                          \
    for (int mf = 0; mf < 4; ++mf) {                                           \
      bf16x8 af = *(const bf16x8*)&lA[aoff[mf]];                               \
      _Pragma("unroll")                                                        \
      for (int nf = 0; nf < 6; ++nf)                                           \
        acc[mf][nf] = __builtin_amdgcn_mfma_f32_16x16x32_bf16(af, bfr[nf], acc[mf][nf], 0, 0, 0); \
    }                                                                          \
    __builtin_amdgcn_s_setprio(0);                                             \
  }

  FSTG(0); FSTG(1);
  int t = 0;
  for (; t < NT - 2; ++t) {
    FSTG(t + 2);
    asm volatile("s_waitcnt vmcnt(10)" ::: "memory");
    fbar();           // all waves' tile-t writes now in LDS
    FCMP(t);
    fbar();           // all waves done reading slot t%3 before it is re-staged
  }
  asm volatile("s_waitcnt vmcnt(5)" ::: "memory");
  fbar();
  FCMP(t); ++t;
  fbar();
  asm volatile("s_waitcnt vmcnt(0)" ::: "memory");
  fbar();
  FCMP(t);
#undef FSTG
#undef FCMP

#pragma unroll
  for (int mf = 0; mf < 4; ++mf) {
    int row = m0 + wr * 64 + mf * 16 + lg * 4;
#pragma unroll
    for (int nf = 0; nf < 6; ++nf) {
      int col = n0 + wc * 96 + nf * 16 + lr;
      float b = bo[col];
#pragma unroll
      for (int j = 0; j < 4; ++j) {
        int s = row + j;
        int orow = (s >= TXT) ? (s - TXT) : (VIDN + s);
        Cout[(size_t)orow * HID + col] = acc[mf][nf][j] + b;
      }
    }
  }
}

// ---------------- LayerNorm + head-indexed RoPE ----------------
// one wave per (s, h, qk): LN over 64 dims, rope for s>=TXT, Q scaled by QSCALE.
// ROUND-21: input is now bf16 (halved read traffic).
__global__ __launch_bounds__(256) void ln_rope_kernel(
    const unsigned short* __restrict__ QK,
    const float* __restrict__ bq, const float* __restrict__ bk,
    const float* __restrict__ gq, const float* __restrict__ bgq,
    const float* __restrict__ gk, const float* __restrict__ bgk,
    const float* __restrict__ freqs,
    unsigned short* __restrict__ Qh, unsigned short* __restrict__ Kh)
{
  int wid = blockIdx.x * 4 + (threadIdx.x >> 6);
  int lane = threadIdx.x & 63;
  int s = wid / 96;
  int rem = wid - s * 96;
  int h = rem >> 1, qk = rem & 1;
  int col = h * 64 + lane;
  float x = bf2f(QK[(size_t)s * 6144 + qk * 3072 + col]) + (qk ? bk[col] : bq[col]);
  float m = x;
#pragma unroll
  for (int msk = 1; msk < 64; msk <<= 1) m += __shfl_xor(m, msk);
  float mu = m * (1.0f / 64.0f);
  float xc = x - mu;
  float v = xc * xc;
#pragma unroll
  for (int msk = 1; msk < 64; msk <<= 1) v += __shfl_xor(v, msk);
  float rstd = rsqrtf(v * (1.0f / 64.0f) + 1e-5f);
  float y = xc * rstd * (qk ? gk[lane] : gq[lane]) + (qk ? bgk[lane] : bgq[lane]);
  if (s >= TXT) {
    // out[2d+j] = f[h][d][j][0]*x[2d] + f[h][d][j][1]*x[2d+1]; freqs head-indexed
    float p = __shfl_xor(y, 1);
    float xe = (lane & 1) ? p : y;
    float xo = (lane & 1) ? y : p;
    int base = h * 128 + (lane >> 1) * 4 + (lane & 1) * 2;
    y = freqs[base] * xe + freqs[base + 1] * xo;
  }
  if (!qk) y *= QSCALE;  // fold attention scale (and log2e for exp2-softmax) into Q
  (qk ? Kh : Qh)[((size_t)h * SEQ + s) * 64 + lane] = f2bf(y);
}

// ---------------- flash attention (swapped-QK^T softmax) ----------------
// ROUND-17 version (best measured ~90 us; QBLK=256 regressed: q-groups
// serialized through shared pl slice + VGPR pressure).
// grid: h * 16 q-tiles; 8 waves x 16 q-rows (QBLK=128); BKV=64; D=64.
// Double-buffered K/V staging with counted vmcnt: { FSTAGE(t+1)=2 gloads;
// vmcnt(2); fbar; compute(t); fbar }. Q-loads issue BEFORE FSTAGE(0).
// St = mfma(K,Q) puts q on lane&15: row-reduce = 15 in-reg ops + 2 shuffles.
__global__ __launch_bounds__(512) void fattn_kernel(
    const unsigned short* __restrict__ Qh, const unsigned short* __restrict__ Kh,
    const unsigned short* __restrict__ Vt, unsigned short* __restrict__ ctx)
{
  __shared__ unsigned short kt[2][2][64][32];  // [slot][half][row][col]
  __shared__ unsigned short vt[2][2][64][32];
  __shared__ unsigned short pl[8][16][72];
  const int h = blockIdx.x >> 4;
  const int q0 = (blockIdx.x & 15) * 128;
  const int tid = threadIdx.x, w = tid >> 6, lane = tid & 63, lr = lane & 15, lg = lane >> 4;

  bf16x8 qf0, qf1;
  {
    const unsigned short* qp = Qh + ((size_t)h * SEQ + q0 + w * 16 + lr) * 64 + lg * 8;
    qf0 = *(const bf16x8*)qp;
    qf1 = *(const bf16x8*)(qp + 32);
  }
  f32x4 oacc[4] = {};
  float mrun = -1e30f, lrun = 0.f;   // this lane's q-row = q0 + w*16 + lr

  // per-thread staging addresses (fixed row/half/col; kv advances the source)
  const int soff = tid * 16;
  const int shalf = soff >> 12;
  const int srem = soff & 4095;
  const int srow = srem >> 6, scb = srem & 63;
  const unsigned short* Ksrc = Kh + ((size_t)h * SEQ + srow) * 64 + shalf * 32 + (scb >> 1);
  const unsigned short* Vsrc = Vt + ((size_t)(h * 64 + srow)) * SEQ + shalf * 32 + (scb >> 1);

#define FSTAGE(t)                                                              \
  {                                                                            \
    const int sl_ = (t) & 1;                                                   \
    const int kv0_ = (t) << 6;                                                 \
    gload16(Ksrc + (size_t)kv0_ * 64, (char*)kt + sl_ * 8192 + soff);          \
    gload16(Vsrc + kv0_, (char*)vt + sl_ * 8192 + soff);                       \
  }

  FSTAGE(0);
  for (int t = 0; t < 32; ++t) {
    const int sl = t & 1;
    if (t < 31) {
      FSTAGE(t + 1);
      asm volatile("s_waitcnt vmcnt(2)" ::: "memory");
    } else {
      asm volatile("s_waitcnt vmcnt(0)" ::: "memory");
    }
    fbar();   // all waves' tile-t K/V writes now in LDS

    // St[kv][q]: sacc[nf][r] = S[q = lr][kv = t*64 + nf*16 + lg*4 + r]
    f32x4 sacc[4] = {};
    __builtin_amdgcn_s_setprio(1);
#pragma unroll
    for (int nf = 0; nf < 4; ++nf) {
      bf16x8 a0 = *(const bf16x8*)&kt[sl][0][nf * 16 + lr][lg * 8];
      bf16x8 a1 = *(const bf16x8*)&kt[sl][1][nf * 16 + lr][lg * 8];
      sacc[nf] = __builtin_amdgcn_mfma_f32_16x16x32_bf16(a0, qf0, sacc[nf], 0, 0, 0);
      sacc[nf] = __builtin_amdgcn_mfma_f32_16x16x32_bf16(a1, qf1, sacc[nf], 0, 0, 0);
    }
    __builtin_amdgcn_s_setprio(0);

    // tile max over the 16 in-register kv values, then xor16/xor32
    float mx;
    {
      float t0 = fmaxf(fmaxf(sacc[0][0], sacc[0][1]), fmaxf(sacc[0][2], sacc[0][3]));
      float t1 = fmaxf(fmaxf(sacc[1][0], sacc[1][1]), fmaxf(sacc[1][2], sacc[1][3]));
      float t2 = fmaxf(fmaxf(sacc[2][0], sacc[2][1]), fmaxf(sacc[2][2], sacc[2][3]));
      float t3 = fmaxf(fmaxf(sacc[3][0], sacc[3][1]), fmaxf(sacc[3][2], sacc[3][3]));
      mx = fmaxf(fmaxf(t0, t1), fmaxf(t2, t3));
    }
    mx = fmaxf(mx, __shfl_xor(mx, 16));
    mx = fmaxf(mx, __shfl_xor(mx, 32));

    // defer-max (log2 units): only rescale when max grew past threshold
    if (!__all(mx <= mrun + 8.0f)) {
      float mn = fmaxf(mrun, mx);
      float corr = exp2f(mrun - mn);
      lrun *= corr;
      mrun = mn;
      float c0 = __shfl(corr, lg * 4 + 0);
      float c1 = __shfl(corr, lg * 4 + 1);
      float c2 = __shfl(corr, lg * 4 + 2);
      float c3 = __shfl(corr, lg * 4 + 3);
#pragma unroll
      for (int df = 0; df < 4; ++df) {
        oacc[df][0] *= c0; oacc[df][1] *= c1;
        oacc[df][2] *= c2; oacc[df][3] *= c3;
      }
    }

    // P = exp2(S - mrun); row-sum; pack to bf16 and write P[q][kv] as b64
    float pr[4][4];
#pragma unroll
    for (int nf = 0; nf < 4; ++nf)
#pragma unroll
      for (int r = 0; r < 4; ++r)
        pr[nf][r] = exp2f(sacc[nf][r] - mrun);
    float rs;
    {
      float s0 = (pr[0][0] + pr[0][1]) + (pr[0][2] + pr[0][3]);
      float s1 = (pr[1][0] + pr[1][1]) + (pr[1][2] + pr[1][3]);
      float s2 = (pr[2][0] + pr[2][1]) + (pr[2][2] + pr[2][3]);
      float s3 = (pr[3][0] + pr[3][1]) + (pr[3][2] + pr[3][3]);
      rs = (s0 + s1) + (s2 + s3);
    }
    rs += __shfl_xor(rs, 16);
    rs += __shfl_xor(rs, 32);
    lrun += rs;

#pragma unroll
    for (int nf = 0; nf < 4; ++nf) {
      union { __hip_bfloat162 h; unsigned int u; } c0, c1;
      c0.h = __float22bfloat162_rn(make_float2(pr[nf][0], pr[nf][1]));
      c1.h = __float22bfloat162_rn(make_float2(pr[nf][2], pr[nf][3]));
      uint2 pw; pw.x = c0.u; pw.y = c1.u;
      *(uint2*)&pl[w][lr][nf * 16 + lg * 4] = pw;
    }
    // no barrier: pl slice is per-wave; lgkmcnt orders write->read

    bf16x8 pa0 = *(const bf16x8*)&pl[w][lr][lg * 8];
    bf16x8 pa1 = *(const bf16x8*)&pl[w][lr][32 + lg * 8];
    __builtin_amdgcn_s_setprio(1);
#pragma unroll
    for (int df = 0; df < 4; ++df) {
      bf16x8 v0 = *(const bf16x8*)&vt[sl][0][df * 16 + lr][lg * 8];
      bf16x8 v1 = *(const bf16x8*)&vt[sl][1][df * 16 + lr][lg * 8];
      oacc[df] = __builtin_amdgcn_mfma_f32_16x16x32_bf16(pa0, v0, oacc[df], 0, 0, 0);
      oacc[df] = __builtin_amdgcn_mfma_f32_16x16x32_bf16(pa1, v1, oacc[df], 0, 0, 0);
    }
    __builtin_amdgcn_s_setprio(0);

    fbar();   // all waves done reading slot sl before it is re-staged
  }
#undef FSTAGE

  // epilogue: move 1/lrun (at q=lane&15 layout) to C-layout rows via shfl
  float linv = 1.0f / lrun;
  float i0 = __shfl(linv, lg * 4 + 0);
  float i1 = __shfl(linv, lg * 4 + 1);
  float i2 = __shfl(linv, lg * 4 + 2);
  float i3 = __shfl(linv, lg * 4 + 3);
#pragma unroll
  for (int df = 0; df < 4; ++df) {
    int s = q0 + w * 16 + lg * 4;
    int dcol = h * 64 + df * 16 + lr;
    ctx[(size_t)(s + 0) * HID + dcol] = f2bf(oacc[df][0] * i0);
    ctx[(size_t)(s + 1) * HID + dcol] = f2bf(oacc[df][1] * i1);
    ctx[(size_t)(s + 2) * HID + dcol] = f2bf(oacc[df][2] * i2);
    ctx[(size_t)(s + 3) * HID + dcol] = f2bf(oacc[df][3] * i3);
  }
}

extern "C" void kernel_launch(void* const* d_in, const int* in_sizes, int n_in,
                              void* d_out, int out_size, void* d_ws, size_t ws_size,
                              hipStream_t stream) {
  const float* combined = (const float*)d_in[0];
  const float* freqs    = (const float*)d_in[1];
  const float* Wq  = (const float*)d_in[2];
  const float* bq  = (const float*)d_in[3];
  const float* Wk  = (const float*)d_in[4];
  const float* bk  = (const float*)d_in[5];
  const float* Wv  = (const float*)d_in[6];
  const float* bv  = (const float*)d_in[7];
  const float* Wo  = (const float*)d_in[8];
  const float* bo  = (const float*)d_in[9];
  const float* gq  = (const float*)d_in[10];
  const float* bgq = (const float*)d_in[11];
  const float* gk  = (const float*)d_in[12];
  const float* bgk = (const float*)d_in[13];
  float* out = (float*)d_out;  // reference output dtype is float32

  char* ws = (char*)d_ws;
  unsigned short* Abf  = (unsigned short*)ws; ws += (size_t)SEQ * HID * 2;    // reused as ctx
  unsigned short* Wqkv = (unsigned short*)ws; ws += (size_t)3 * HID * HID * 2;
  unsigned short* QK   = (unsigned short*)ws; ws += (size_t)SEQ * 6144 * 2;   // bf16 now
  unsigned short* Qh   = (unsigned short*)ws; ws += (size_t)NH * SEQ * HD * 2;
  unsigned short* Kh   = (unsigned short*)ws; ws += (size_t)NH * SEQ * HD * 2;
  unsigned short* Vt   = (unsigned short*)ws; ws += (size_t)NH * HD * SEQ * 2;
  unsigned short* Wob  = (unsigned short*)ws; ws += (size_t)HID * HID * 2;
  unsigned short* ctx  = Abf;                   // alias: Abf dead after QKV GEMM

  // combined + Wq + Wk + Wv + Wo -> bf16 in one launch
  cvt5_kernel<<<(SEQ * HID) / 1024 + 4 * (HID * HID) / 1024, 256, 0, stream>>>(
      combined, Wq, Wk, Wv, Wo, Abf, Wqkv, Wob);

  // QKV GEMM: M=2048, N=9216, K=3072 -> 16x36 = 576 blocks of 128x256, BK=64
  gemm8p<<<16 * 36, 512, 0, stream>>>(Abf, Wqkv, HID, 36, QK, Vt, bv);

  // LN + rope: 2048*48*2 waves (bf16 input)
  ln_rope_kernel<<<(SEQ * NH * 2) / 4, 256, 0, stream>>>(QK, bq, bk, gq, bgq, gk, bgk, freqs, Qh, Kh);

  // flash attention: 48 heads x 16 q-tiles of 128 rows, 512 threads
  fattn_kernel<<<NH * 16, 512, 0, stream>>>(Qh, Kh, Vt, ctx);

  // final GEMM: M=2048, N=3072, K=3072 -> 16x16 = 256 blocks of 128x192 (1/CU)
  gemmF<<<16 * 16, 256, 0, stream>>>(ctx, Wob, out, bo);
}